// Round 4
// baseline (4586.449 us; speedup 1.0000x reference)
//
#include <hip/hip_runtime.h>
#include <hip/hip_bf16.h>

typedef __hip_bfloat16 bf16;
typedef unsigned char u8;
typedef __attribute__((ext_vector_type(8))) short short8;
typedef __attribute__((ext_vector_type(16))) float f32x16;
#define DI __device__ __forceinline__

union BF8 { int4 v; short8 s; bf16 h[8]; };
union BF4 { unsigned long long u; bf16 h[4]; };

// ws layout (bytes):
// phase A (proj/attn):  projchunk bf16 [6][128][64][1024] @ 0           (100,663,296)
//                       cA bf16 [128][256][1024]          @ 100,663,296 ( 67,108,864)
//                       cB u8   [128][256][1024]          @ 167,772,160 ( 33,554,432)
// phase B (transpose):  cAT bf16 [128][1024 pos][256 ch]  @ 0           ( 67,108,864)
//                       cBT u8   [128][1024 pos][256 ch]  @ 67,108,864  ( 33,554,432)
// phase C (convs):      x3 @100,663,296  x5 @134,217,728  x7 @167,772,160  x1 @201,326,592
// parts f32             @ 234,881,024 (32 KB)
// wb3/wb5/wb7 bf16 [tap][128 oc][512 ic] @ 234,913,792 / 236,093,440 / 239,370,240
// w1T bf16 [128][512] @ 245,792,768   (end 245,923,840 < 256 MiB)

// ---------------------------------------------------------------- weight prep
__global__ __launch_bounds__(256) void prep_w_kernel(
    const float* __restrict__ w3, const float* __restrict__ w5,
    const float* __restrict__ w7, const float* __restrict__ w1,
    bf16* __restrict__ wb3, bf16* __restrict__ wb5,
    bf16* __restrict__ wb7, bf16* __restrict__ w1T)
{
  const int N3 = 9 * 65536, N5 = 25 * 65536, N7 = 49 * 65536, N1 = 65536;
  const int total = N3 + N5 + N7 + N1;
  for (int i = blockIdx.x * 256 + threadIdx.x; i < total; i += gridDim.x * 256) {
    if (i < N3) {
      int tap = i >> 16, rem = i & 65535;
      wb3[i] = __float2bfloat16(w3[(size_t)rem * 9 + tap]);
    } else if (i < N3 + N5) {
      int k = i - N3; int tap = k >> 16, rem = k & 65535;
      wb5[k] = __float2bfloat16(w5[(size_t)rem * 25 + tap]);
    } else if (i < N3 + N5 + N7) {
      int k = i - N3 - N5; int tap = k >> 16, rem = k & 65535;
      wb7[k] = __float2bfloat16(w7[(size_t)rem * 49 + tap]);
    } else {
      int k = i - N3 - N5 - N7;
      w1T[k] = __float2bfloat16(w1[k]);
    }
  }
}

// ---------------------------------------------------------------- projections (64-ch chunk)
__global__ __launch_bounds__(256) void proj_chunk_kernel(
    const float* __restrict__ st, const float* __restrict__ phy,
    const float* __restrict__ w0, const float* __restrict__ b0,
    const float* __restrict__ w1, const float* __restrict__ b1,
    const float* __restrict__ w2, const float* __restrict__ b2,
    const float* __restrict__ w3, const float* __restrict__ b3,
    const float* __restrict__ w4, const float* __restrict__ b4,
    const float* __restrict__ w5, const float* __restrict__ b5,
    bf16* __restrict__ pc, int cb)
{
  __shared__ __align__(16) bf16 Xs[128][128];
  __shared__ __align__(16) bf16 Ws[128][64];
  const int pt = blockIdx.x, b = blockIdx.y;
  const int tid = threadIdx.x;
  const int c0 = (tid >> 4) * 4;
  const int p0 = (tid & 15) * 8;

  #pragma unroll
  for (int mat = 0; mat < 6; ++mat) {
    const float* Wm; const float* Bm; const float* X;
    switch (mat) {
      case 0: Wm = w0; Bm = b0; X = st;  break;
      case 1: Wm = w1; Bm = b1; X = st;  break;
      case 2: Wm = w2; Bm = b2; X = st;  break;
      case 3: Wm = w3; Bm = b3; X = phy; break;
      case 4: Wm = w4; Bm = b4; X = phy; break;
      default:Wm = w5; Bm = b5; X = phy; break;
    }
    __syncthreads();
    if (mat == 0 || mat == 3) {
      for (int e = tid; e < 128 * 128; e += 256) {
        int i = e >> 7, p = e & 127;
        Xs[i][p] = __float2bfloat16(X[((size_t)b * 128 + i) * 1024 + pt * 128 + p]);
      }
    }
    for (int e = tid; e < 64 * 128; e += 256) {
      int c = e >> 7, i = e & 127;
      Ws[i][c] = __float2bfloat16(Wm[(cb + c) * 128 + i]);
    }
    __syncthreads();

    float acc[4][8];
    #pragma unroll
    for (int a = 0; a < 4; ++a)
      #pragma unroll
      for (int d = 0; d < 8; ++d) acc[a][d] = 0.f;

    #pragma unroll 2
    for (int i = 0; i < 128; ++i) {
      BF4 wv; wv.u = *(const unsigned long long*)&Ws[i][c0];
      BF8 xv; xv.v = *(const int4*)&Xs[i][p0];
      float wf[4], xf[8];
      #pragma unroll
      for (int j = 0; j < 4; ++j) wf[j] = __bfloat162float(wv.h[j]);
      #pragma unroll
      for (int j = 0; j < 8; ++j) xf[j] = __bfloat162float(xv.h[j]);
      #pragma unroll
      for (int cc = 0; cc < 4; ++cc)
        #pragma unroll
        for (int pp = 0; pp < 8; ++pp)
          acc[cc][pp] = fmaf(wf[cc], xf[pp], acc[cc][pp]);
    }
    #pragma unroll
    for (int cc = 0; cc < 4; ++cc) {
      float bias = Bm[cb + c0 + cc];
      BF8 pk;
      #pragma unroll
      for (int pp = 0; pp < 8; ++pp) pk.h[pp] = __float2bfloat16(acc[cc][pp] + bias);
      *(int4*)&pc[(((size_t)mat * 128 + b) * 64 + c0 + cc) * 1024 + pt * 128 + p0] = pk.v;
    }
  }
}

// ---------------------------------------------------------------- attention helpers
DI void mm32(const float* A, int sa, const float* Bm, int sb,
             float acc[4][4], int r0, int c0)
{
  #pragma unroll 4
  for (int w = 0; w < 32; ++w) {
    float qv[4], kv[4];
    *(float4*)qv = *(const float4*)(A + w * sa + r0);
    *(float4*)kv = *(const float4*)(Bm + w * sb + c0);
    #pragma unroll
    for (int i = 0; i < 4; ++i)
      #pragma unroll
      for (int j = 0; j < 4; ++j)
        acc[i][j] = fmaf(qv[i], kv[j], acc[i][j]);
  }
}

DI void softmax4(float acc[4][4])
{
  #pragma unroll
  for (int i = 0; i < 4; ++i) {
    float m = fmaxf(fmaxf(acc[i][0], acc[i][1]), fmaxf(acc[i][2], acc[i][3]));
    m = fmaxf(m, __shfl_xor(m, 1));
    m = fmaxf(m, __shfl_xor(m, 2));
    m = fmaxf(m, __shfl_xor(m, 4));
    float s = 0.f;
    #pragma unroll
    for (int j = 0; j < 4; ++j) { acc[i][j] = __expf(acc[i][j] - m); s += acc[i][j]; }
    s += __shfl_xor(s, 1); s += __shfl_xor(s, 2); s += __shfl_xor(s, 4);
    float rs = 1.0f / s;
    #pragma unroll
    for (int j = 0; j < 4; ++j) acc[i][j] *= rs;
  }
}

template<bool U8OUT>
DI void attn_one(const float* Qt, const float* K, const float* V, float (*At)[36],
                 const float* resid, void* outp, int r0, int c0)
{
  float acc[4][4] = {};
  mm32(Qt, 36, K, 32, acc, r0, c0);
  softmax4(acc);
  __syncthreads();
  #pragma unroll
  for (int j = 0; j < 4; ++j)
    *(float4*)&At[c0 + j][r0] = make_float4(acc[0][j], acc[1][j], acc[2][j], acc[3][j]);
  __syncthreads();
  float o[4][4] = {};
  mm32(&At[0][0], 36, V, 32, o, r0, c0);
  softmax4(o);
  if constexpr (!U8OUT) {
    bf16* op = (bf16*)outp;
    if (resid) {
      #pragma unroll
      for (int i = 0; i < 4; ++i) {
        float4 rv = *(const float4*)&resid[(r0 + i) * 32 + c0];
        o[i][0] += rv.x; o[i][1] += rv.y; o[i][2] += rv.z; o[i][3] += rv.w;
      }
    }
    #pragma unroll
    for (int i = 0; i < 4; ++i) {
      BF4 pk;
      #pragma unroll
      for (int j = 0; j < 4; ++j) pk.h[j] = __float2bfloat16(o[i][j]);
      *(unsigned long long*)&op[(r0 + i) * 32 + c0] = pk.u;
    }
  } else {
    u8* op = (u8*)outp;
    #pragma unroll
    for (int i = 0; i < 4; ++i) {
      unsigned pk = 0;
      #pragma unroll
      for (int j = 0; j < 4; ++j) {
        unsigned bv = (unsigned)fminf(o[i][j] * 256.f + 0.5f, 255.f);
        pk |= bv << (8 * j);
      }
      *(unsigned*)&op[(r0 + i) * 32 + c0] = pk;
    }
  }
}

// ---------------------------------------------------------------- attention (64-ch chunk)
__global__ __launch_bounds__(64) void attn_chunk_kernel(
    const bf16* __restrict__ pc,
    const float* __restrict__ st, const float* __restrict__ phy,
    bf16* __restrict__ cA, u8* __restrict__ cB, int cb)
{
  __shared__ __align__(16) float Qst[32][36], Qphy[32][36];
  __shared__ __align__(16) float Kst[32][32], Kphy[32][32];
  __shared__ __align__(16) float Vst[32][32], Vphy[32][32];
  __shared__ __align__(16) float At[32][36];
  const int cl = blockIdx.x, b = blockIdx.y;
  const int c = cb + cl;
  const int lane = threadIdx.x;
  const size_t mstride = (size_t)128 * 64 * 1024;
  const bf16* p0 = pc + ((size_t)b * 64 + cl) * 1024;
  const size_t bc = ((size_t)b * 128 + c) * 1024;

  for (int e = lane; e < 1024; e += 64) {
    int h = e >> 5, w = e & 31;
    Qst[w][h]  = __bfloat162float(p0[e]);
    Kst[h][w]  = __bfloat162float(p0[mstride + e]);
    Vst[h][w]  = __bfloat162float(p0[2 * mstride + e]);
    Qphy[w][h] = __bfloat162float(p0[3 * mstride + e]);
    Kphy[h][w] = __bfloat162float(p0[4 * mstride + e]);
    Vphy[h][w] = __bfloat162float(p0[5 * mstride + e]);
  }
  __syncthreads();
  const int r0 = (lane >> 3) * 4, c0 = (lane & 7) * 4;
  bf16* aA = cA + (size_t)b * 256 * 1024 + (size_t)c * 1024;
  u8*   aB = cB + (size_t)b * 256 * 1024 + (size_t)c * 1024;

  attn_one<false>(&Qst[0][0],  &Kst[0][0],  &Vst[0][0],  At, st + bc,  aA,               r0, c0);
  attn_one<false>(&Qphy[0][0], &Kphy[0][0], &Vphy[0][0], At, phy + bc, aA + 128 * 1024,  r0, c0);
  attn_one<true >(&Qphy[0][0], &Kst[0][0],  &Vst[0][0],  At, nullptr,  aB,               r0, c0);
  attn_one<true >(&Qst[0][0],  &Kphy[0][0], &Vphy[0][0], At, nullptr,  aB + 128 * 1024,  r0, c0);
}

// ---------------------------------------------------------------- concat transpose -> [b][pos][ch]
__global__ __launch_bounds__(256) void transpose_kernel(
    const bf16* __restrict__ cA, const u8* __restrict__ cB,
    bf16* __restrict__ cAT, u8* __restrict__ cBT)
{
  __shared__ __align__(16) short Tb[64 * 72];
  __shared__ __align__(16) u8 T8[64 * 80];
  const int x = blockIdx.x, b = blockIdx.y;
  const int cht = x >> 4, post = x & 15;
  const int pos0 = post * 64;
  const int tid = threadIdx.x;
  const int rowi = tid >> 2, sub = tid & 3;

  if (cht < 4) {
    const int ch0 = cht * 64;
    const bf16* src = cA + ((size_t)b * 256 + ch0 + rowi) * 1024 + pos0 + sub * 16;
    *(int4*)&Tb[rowi * 72 + sub * 16]     = *(const int4*)src;
    *(int4*)&Tb[rowi * 72 + sub * 16 + 8] = *(const int4*)(src + 8);
    __syncthreads();
    short tmp[16];
    #pragma unroll
    for (int j = 0; j < 16; ++j) tmp[j] = Tb[(sub * 16 + j) * 72 + rowi];
    bf16* dst = cAT + ((size_t)b * 1024 + pos0 + rowi) * 256 + ch0 + sub * 16;
    *(int4*)dst       = ((int4*)tmp)[0];
    *(int4*)(dst + 8) = ((int4*)tmp)[1];
  } else {
    const int ch0 = (cht - 4) * 64;
    const u8* src = cB + ((size_t)b * 256 + ch0 + rowi) * 1024 + pos0 + sub * 16;
    *(int4*)&T8[rowi * 80 + sub * 16] = *(const int4*)src;
    __syncthreads();
    u8 tmp[16];
    #pragma unroll
    for (int j = 0; j < 16; ++j) tmp[j] = T8[(sub * 16 + j) * 80 + rowi];
    u8* dst = cBT + ((size_t)b * 1024 + pos0 + rowi) * 256 + ch0 + sub * 16;
    *(int4*)dst = *(int4*)tmp;
  }
}

// ---------------------------------------------------------------- MFMA conv k=3/5/7
// Block: 256 thr (4 waves), covers 128 oc x 8 rows x 32 cols. Grid (4, 128).
// LDS: Xs[ppos][40 shorts] (32 ic + pad), 16B slots XOR-swizzled by (ppos>>2)&3
//   -> 16 banks x 2-way on reads AND writes (2-way is free, m136).
// Per tap per wave: 4 ds_read_b128 (B), 8 global dwordx4 (A, L1/L2-hit), 16 MFMA.
template<int KS>
__global__ __launch_bounds__(256, 2) void conv_mfma(
    const bf16* __restrict__ cAT, const u8* __restrict__ cBT,
    const bf16* __restrict__ wt, bf16* __restrict__ xout,
    float* __restrict__ partials)
{
  constexpr int H0 = KS / 2;
  constexpr int PR = 8 + 2 * H0;
  constexpr int PC = 32 + 2 * H0;
  constexpr int PPOS = PR * PC;
  __shared__ __align__(16) short Xs[PPOS * 40];
  __shared__ float rs[256], rq[256];
  const int pt = blockIdx.x, b = blockIdx.y;
  const int r0 = pt * 8;
  const int tid = threadIdx.x;
  const int wave = tid >> 6, lane = tid & 63;
  const int col = lane & 31, kg = lane >> 5;

  f32x16 acc[4][2];
  #pragma unroll
  for (int i = 0; i < 4; ++i)
    #pragma unroll
    for (int j = 0; j < 2; ++j)
      #pragma unroll
      for (int e = 0; e < 16; ++e) acc[i][j][e] = 0.f;

  for (int cc = 0; cc < 16; ++cc) {
    const int ic0 = cc * 32;
    __syncthreads();
    for (int g = tid; g < PPOS * 4; g += 256) {
      int ppos = g >> 2, part = g & 3;
      int prow = ppos / PC, pcol = ppos - prow * PC;
      int r = r0 + prow - H0, c = pcol - H0;
      int4 val = make_int4(0, 0, 0, 0);
      if ((unsigned)r < 32u && (unsigned)c < 32u) {
        size_t pbase = ((size_t)b * 1024 + r * 32 + c) * 256;
        if (ic0 < 256) {
          val = *(const int4*)&cAT[pbase + ic0 + part * 8];
        } else {
          const u8* s = &cBT[pbase + (ic0 - 256) + part * 8];
          unsigned lo = *(const unsigned*)s, hi = *(const unsigned*)(s + 4);
          BF8 t;
          #pragma unroll
          for (int j = 0; j < 4; ++j) t.h[j]     = __float2bfloat16((float)((lo >> (8 * j)) & 255u) * 0.00390625f);
          #pragma unroll
          for (int j = 0; j < 4; ++j) t.h[4 + j] = __float2bfloat16((float)((hi >> (8 * j)) & 255u) * 0.00390625f);
          val = t.v;
        }
      }
      int slot = part ^ ((ppos >> 2) & 3);
      *(int4*)&Xs[ppos * 40 + slot * 8] = val;
    }
    __syncthreads();

    const bf16* wl = wt + (size_t)col * 512 + ic0 + kg * 8;  // lane base into [tap][oc][ic]
    #pragma unroll
    for (int ky = 0; ky < KS; ++ky) {
      #pragma unroll
      for (int kx = 0; kx < KS; ++kx) {
        const int tap = ky * KS + kx;
        short8 bfr[2][2];
        #pragma unroll
        for (int rr = 0; rr < 2; ++rr) {
          int ppos = (2 * wave + rr + ky) * PC + col + kx;
          int sw = (ppos >> 2) & 3;
          #pragma unroll
          for (int kt = 0; kt < 2; ++kt) {
            int part = kt * 2 + kg;
            bfr[rr][kt] = *(const short8*)&Xs[ppos * 40 + (part ^ sw) * 8];
          }
        }
        #pragma unroll
        for (int ob = 0; ob < 4; ++ob) {
          BF8 a0, a1;
          a0.v = *(const int4*)&wl[((size_t)tap * 128 + ob * 32) * 512];
          a1.v = *(const int4*)&wl[((size_t)tap * 128 + ob * 32) * 512 + 16];
          acc[ob][0] = __builtin_amdgcn_mfma_f32_32x32x16_bf16(a0.s, bfr[0][0], acc[ob][0], 0, 0, 0);
          acc[ob][1] = __builtin_amdgcn_mfma_f32_32x32x16_bf16(a0.s, bfr[1][0], acc[ob][1], 0, 0, 0);
          acc[ob][0] = __builtin_amdgcn_mfma_f32_32x32x16_bf16(a1.s, bfr[0][1], acc[ob][0], 0, 0, 0);
          acc[ob][1] = __builtin_amdgcn_mfma_f32_32x32x16_bf16(a1.s, bfr[1][1], acc[ob][1], 0, 0, 0);
        }
      }
    }
  }

  float lsum = 0.f, lsq = 0.f;
  #pragma unroll
  for (int ob = 0; ob < 4; ++ob)
    #pragma unroll
    for (int rr = 0; rr < 2; ++rr) {
      const int row = r0 + 2 * wave + rr;
      #pragma unroll
      for (int r = 0; r < 16; ++r) {
        const int oc = ob * 32 + (r & 3) + 8 * (r >> 2) + 4 * kg;
        float v = acc[ob][rr][r];
        xout[((size_t)b * 128 + oc) * 1024 + row * 32 + col] = __float2bfloat16(v);
        lsum += v; lsq += v * v;
      }
    }
  rs[tid] = lsum; rq[tid] = lsq;
  __syncthreads();
  for (int s = 128; s > 0; s >>= 1) {
    if (tid < s) { rs[tid] += rs[tid + s]; rq[tid] += rq[tid + s]; }
    __syncthreads();
  }
  if (tid == 0) {
    partials[((size_t)b * 4 + pt) * 2]     = rs[0];
    partials[((size_t)b * 4 + pt) * 2 + 1] = rq[0];
  }
}

// ---------------------------------------------------------------- MFMA conv k=1 + b1
__global__ __launch_bounds__(256) void conv1_mfma(
    const bf16* __restrict__ cAT, const u8* __restrict__ cBT,
    const bf16* __restrict__ w1T, const float* __restrict__ b1,
    bf16* __restrict__ xout, float* __restrict__ partials)
{
  __shared__ float rs[256], rq[256];
  const int pt = blockIdx.x, b = blockIdx.y;
  const int tid = threadIdx.x, wave = tid >> 6, lane = tid & 63;
  const int col = lane & 31, kg = lane >> 5;
  const int pos = pt * 128 + wave * 32 + col;

  f32x16 acc[4];
  #pragma unroll
  for (int i = 0; i < 4; ++i)
    #pragma unroll
    for (int e = 0; e < 16; ++e) acc[i][e] = 0.f;

  const bf16* wbase = w1T + (size_t)col * 512 + kg * 8;
  const size_t pbase = ((size_t)b * 1024 + pos) * 256;

  #pragma unroll 2
  for (int kst = 0; kst < 32; ++kst) {
    short8 bfr;
    if (kst < 16) {
      bfr = *(const short8*)&cAT[pbase + kst * 16 + kg * 8];
    } else {
      const u8* s = &cBT[pbase + (kst - 16) * 16 + kg * 8];
      unsigned lo = *(const unsigned*)s, hi = *(const unsigned*)(s + 4);
      BF8 t;
      #pragma unroll
      for (int j = 0; j < 4; ++j) t.h[j]     = __float2bfloat16((float)((lo >> (8 * j)) & 255u) * 0.00390625f);
      #pragma unroll
      for (int j = 0; j < 4; ++j) t.h[4 + j] = __float2bfloat16((float)((hi >> (8 * j)) & 255u) * 0.00390625f);
      bfr = t.s;
    }
    #pragma unroll
    for (int mf = 0; mf < 4; ++mf) {
      BF8 a; a.v = *(const int4*)&wbase[((size_t)mf * 32) * 512 + kst * 16];
      acc[mf] = __builtin_amdgcn_mfma_f32_32x32x16_bf16(a.s, bfr, acc[mf], 0, 0, 0);
    }
  }

  float lsum = 0.f, lsq = 0.f;
  #pragma unroll
  for (int mf = 0; mf < 4; ++mf) {
    #pragma unroll
    for (int r = 0; r < 16; ++r) {
      const int oc = mf * 32 + (r & 3) + 8 * (r >> 2) + 4 * kg;
      float v = acc[mf][r] + b1[oc];
      xout[((size_t)b * 128 + oc) * 1024 + pos] = __float2bfloat16(v);
      lsum += v; lsq += v * v;
    }
  }
  rs[tid] = lsum; rq[tid] = lsq;
  __syncthreads();
  for (int s = 128; s > 0; s >>= 1) {
    if (tid < s) { rs[tid] += rs[tid + s]; rq[tid] += rq[tid + s]; }
    __syncthreads();
  }
  if (tid == 0) {
    partials[((size_t)b * 8 + pt) * 2]     = rs[0];
    partials[((size_t)b * 8 + pt) * 2 + 1] = rq[0];
  }
}

// ---------------------------------------------------------------- LN + combine
__global__ __launch_bounds__(256) void final_kernel(
    const bf16* __restrict__ x3, const bf16* __restrict__ x5,
    const bf16* __restrict__ x7, const bf16* __restrict__ x1c,
    const float* __restrict__ p3, const float* __restrict__ p5,
    const float* __restrict__ p7, const float* __restrict__ p1,
    const float* __restrict__ g3, const float* __restrict__ be3,
    const float* __restrict__ g5, const float* __restrict__ be5,
    const float* __restrict__ g7, const float* __restrict__ be7,
    const float* __restrict__ g1, const float* __restrict__ be1,
    float* __restrict__ out)
{
  const int blk = blockIdx.x, b = blockIdx.y, tid = threadIdx.x;
  float s3 = 0, q3 = 0, s5 = 0, q5 = 0, s7 = 0, q7 = 0, s1 = 0, q1 = 0;
  #pragma unroll
  for (int i = 0; i < 4; ++i) {
    int o = (b * 4 + i) * 2;
    s3 += p3[o]; q3 += p3[o + 1];
    s5 += p5[o]; q5 += p5[o + 1];
    s7 += p7[o]; q7 += p7[o + 1];
  }
  #pragma unroll
  for (int i = 0; i < 8; ++i) {
    int o = (b * 8 + i) * 2;
    s1 += p1[o]; q1 += p1[o + 1];
  }
  const float inv = 1.0f / 131072.0f;
  float mu3 = s3 * inv, r3 = rsqrtf(fmaxf(q3 * inv - mu3 * mu3, 0.f) + 1e-5f);
  float mu5 = s5 * inv, r5 = rsqrtf(fmaxf(q5 * inv - mu5 * mu5, 0.f) + 1e-5f);
  float mu7 = s7 * inv, r7 = rsqrtf(fmaxf(q7 * inv - mu7 * mu7, 0.f) + 1e-5f);
  float mu1 = s1 * inv, r1 = rsqrtf(fmaxf(q1 * inv - mu1 * mu1, 0.f) + 1e-5f);
  const size_t bb = (size_t)b * 131072;
  for (int it = 0; it < 8; ++it) {
    int e0 = (it * 2048 + blk * 256 + tid) * 8;
    BF8 a3, a5, a7, a1;
    a3.v = *(const int4*)&x3[bb + e0];
    a5.v = *(const int4*)&x5[bb + e0];
    a7.v = *(const int4*)&x7[bb + e0];
    a1.v = *(const int4*)&x1c[bb + e0];
    float G3[8], B3[8], G5[8], B5[8], G7[8], B7[8], G1[8], B1[8];
    *(float4*)&G3[0] = *(const float4*)&g3[e0];  *(float4*)&G3[4] = *(const float4*)&g3[e0 + 4];
    *(float4*)&B3[0] = *(const float4*)&be3[e0]; *(float4*)&B3[4] = *(const float4*)&be3[e0 + 4];
    *(float4*)&G5[0] = *(const float4*)&g5[e0];  *(float4*)&G5[4] = *(const float4*)&g5[e0 + 4];
    *(float4*)&B5[0] = *(const float4*)&be5[e0]; *(float4*)&B5[4] = *(const float4*)&be5[e0 + 4];
    *(float4*)&G7[0] = *(const float4*)&g7[e0];  *(float4*)&G7[4] = *(const float4*)&g7[e0 + 4];
    *(float4*)&B7[0] = *(const float4*)&be7[e0]; *(float4*)&B7[4] = *(const float4*)&be7[e0 + 4];
    *(float4*)&G1[0] = *(const float4*)&g1[e0];  *(float4*)&G1[4] = *(const float4*)&g1[e0 + 4];
    *(float4*)&B1[0] = *(const float4*)&be1[e0]; *(float4*)&B1[4] = *(const float4*)&be1[e0 + 4];
    float res[8];
    #pragma unroll
    for (int j = 0; j < 8; ++j) {
      float v3 = (__bfloat162float(a3.h[j]) - mu3) * r3 * G3[j] + B3[j];
      float v5 = (__bfloat162float(a5.h[j]) - mu5) * r5 * G5[j] + B5[j];
      float v7 = (__bfloat162float(a7.h[j]) - mu7) * r7 * G7[j] + B7[j];
      float m = (v3 + v5 + v7) * (1.0f / 3.0f);
      float sg = 1.0f / (1.0f + __expf(-m));
      float v1 = (__bfloat162float(a1.h[j]) - mu1) * r1 * G1[j] + B1[j];
      res[j] = sg + v1;
    }
    *(float4*)&out[bb + e0]     = make_float4(res[0], res[1], res[2], res[3]);
    *(float4*)&out[bb + e0 + 4] = make_float4(res[4], res[5], res[6], res[7]);
  }
}

// ---------------------------------------------------------------- launch
extern "C" void kernel_launch(void* const* d_in, const int* in_sizes, int n_in,
                              void* d_out, int out_size, void* d_ws, size_t ws_size,
                              hipStream_t stream)
{
  (void)in_sizes; (void)n_in; (void)out_size; (void)ws_size;
  const float* st     = (const float*)d_in[0];
  const float* phy    = (const float*)d_in[1];
  const float* wq_st  = (const float*)d_in[2];
  const float* bq_st  = (const float*)d_in[3];
  const float* wk_st  = (const float*)d_in[4];
  const float* bk_st  = (const float*)d_in[5];
  const float* wv_st  = (const float*)d_in[6];
  const float* bv_st  = (const float*)d_in[7];
  const float* wq_phy = (const float*)d_in[8];
  const float* bq_phy = (const float*)d_in[9];
  const float* wk_phy = (const float*)d_in[10];
  const float* bk_phy = (const float*)d_in[11];
  const float* wv_phy = (const float*)d_in[12];
  const float* bv_phy = (const float*)d_in[13];
  const float* w3  = (const float*)d_in[14];
  const float* g3  = (const float*)d_in[15];
  const float* be3 = (const float*)d_in[16];
  const float* w5  = (const float*)d_in[17];
  const float* g5  = (const float*)d_in[18];
  const float* be5 = (const float*)d_in[19];
  const float* w7  = (const float*)d_in[20];
  const float* g7  = (const float*)d_in[21];
  const float* be7 = (const float*)d_in[22];
  const float* w1  = (const float*)d_in[23];
  const float* g1  = (const float*)d_in[24];
  const float* be1 = (const float*)d_in[25];
  const float* b1  = (const float*)d_in[26];

  char* ws = (char*)d_ws;
  bf16* cAT      = (bf16*)ws;
  u8*   cBT      = (u8*)(ws + 67108864ULL);
  bf16* projchunk = (bf16*)ws;                      // phase A only
  bf16* cA       = (bf16*)(ws + 100663296ULL);      // phase A only
  u8*   cB       = (u8*)(ws + 167772160ULL);        // phase A only
  bf16* x3b      = (bf16*)(ws + 100663296ULL);
  bf16* x5b      = (bf16*)(ws + 134217728ULL);
  bf16* x7b      = (bf16*)(ws + 167772160ULL);
  bf16* x1b      = (bf16*)(ws + 201326592ULL);
  float* parts   = (float*)(ws + 234881024ULL);
  bf16* wb3      = (bf16*)(ws + 234913792ULL);
  bf16* wb5      = (bf16*)(ws + 236093440ULL);
  bf16* wb7      = (bf16*)(ws + 239370240ULL);
  bf16* w1T      = (bf16*)(ws + 245792768ULL);

  prep_w_kernel<<<dim3(2048), 256, 0, stream>>>(w3, w5, w7, w1, wb3, wb5, wb7, w1T);

  for (int g = 0; g < 2; ++g) {
    proj_chunk_kernel<<<dim3(8, 128), 256, 0, stream>>>(st, phy,
        wq_st, bq_st, wk_st, bk_st, wv_st, bv_st,
        wq_phy, bq_phy, wk_phy, bk_phy, wv_phy, bv_phy, projchunk, g * 64);
    attn_chunk_kernel<<<dim3(64, 128), 64, 0, stream>>>(projchunk, st, phy,
        cA, cB, g * 64);
  }
  transpose_kernel<<<dim3(128, 128), 256, 0, stream>>>(cA, cB, cAT, cBT);

  conv_mfma<3><<<dim3(4, 128), 256, 0, stream>>>(cAT, cBT, wb3, x3b, parts);
  conv_mfma<5><<<dim3(4, 128), 256, 0, stream>>>(cAT, cBT, wb5, x5b, parts + 2048);
  conv_mfma<7><<<dim3(4, 128), 256, 0, stream>>>(cAT, cBT, wb7, x7b, parts + 4096);
  conv1_mfma<<<dim3(8, 128), 256, 0, stream>>>(cAT, cBT, w1T, b1, x1b, parts + 6144);

  final_kernel<<<dim3(8, 128), 256, 0, stream>>>(x3b, x5b, x7b, x1b,
      parts, parts + 2048, parts + 4096, parts + 6144,
      g3, be3, g5, be5, g7, be7, g1, be1, (float*)d_out);
}

// Round 5
// 2506.363 us; speedup vs baseline: 1.8299x; 1.8299x over previous
//
#include <hip/hip_runtime.h>
#include <hip/hip_bf16.h>

typedef __hip_bfloat16 bf16;
typedef unsigned char u8;
typedef __attribute__((ext_vector_type(8))) short short8;
typedef __attribute__((ext_vector_type(16))) float f32x16;
#define DI __device__ __forceinline__

union BF8 { int4 v; short8 s; bf16 h[8]; };
union BF4 { unsigned long long u; bf16 h[4]; };

// ws layout (bytes):
// phase A (proj/attn):  projchunk bf16 [6][128][64][1024] @ 0           (100,663,296)
//                       cA bf16 [128][256][1024]          @ 100,663,296 ( 67,108,864)
//                       cB u8   [128][256][1024]          @ 167,772,160 ( 33,554,432)
// phase B (transpose):  cAT bf16 [128][1024 pos][256 ch]  @ 0           ( 67,108,864)
//                       cBT u8   [128][1024 pos][256 ch]  @ 67,108,864  ( 33,554,432)
// phase C (convs):      x3 @100,663,296  x5 @134,217,728  x7 @167,772,160  x1 @201,326,592
// parts f32             @ 234,881,024 (32 KB)
// wb3/wb5/wb7 bf16 [tap][64 icg][128 oc][8 ic] @ 234,913,792 / 236,093,440 / 239,370,240
// w1T bf16 [128][512] @ 245,792,768   (end 245,923,840 < 256 MiB)

// ---------------------------------------------------------------- weight prep
// k-conv weights repacked to [tap][icg(64)][oc(128)][8 ic] for coalesced A-loads.
__global__ __launch_bounds__(256) void prep_w_kernel(
    const float* __restrict__ w3, const float* __restrict__ w5,
    const float* __restrict__ w7, const float* __restrict__ w1,
    bf16* __restrict__ wb3, bf16* __restrict__ wb5,
    bf16* __restrict__ wb7, bf16* __restrict__ w1T)
{
  const int N3 = 9 * 65536, N5 = 25 * 65536, N7 = 49 * 65536, N1 = 65536;
  const int total = N3 + N5 + N7 + N1;
  for (int i = blockIdx.x * 256 + threadIdx.x; i < total; i += gridDim.x * 256) {
    if (i < N3) {
      int tap = i >> 16, rem = i & 65535;
      int icg = rem >> 10, oc = (rem >> 3) & 127, j = rem & 7;
      wb3[i] = __float2bfloat16(w3[(size_t)(oc * 512 + icg * 8 + j) * 9 + tap]);
    } else if (i < N3 + N5) {
      int k = i - N3; int tap = k >> 16, rem = k & 65535;
      int icg = rem >> 10, oc = (rem >> 3) & 127, j = rem & 7;
      wb5[k] = __float2bfloat16(w5[(size_t)(oc * 512 + icg * 8 + j) * 25 + tap]);
    } else if (i < N3 + N5 + N7) {
      int k = i - N3 - N5; int tap = k >> 16, rem = k & 65535;
      int icg = rem >> 10, oc = (rem >> 3) & 127, j = rem & 7;
      wb7[k] = __float2bfloat16(w7[(size_t)(oc * 512 + icg * 8 + j) * 49 + tap]);
    } else {
      int k = i - N3 - N5 - N7;
      w1T[k] = __float2bfloat16(w1[k]);
    }
  }
}

// ---------------------------------------------------------------- projections (64-ch chunk)
__global__ __launch_bounds__(256) void proj_chunk_kernel(
    const float* __restrict__ st, const float* __restrict__ phy,
    const float* __restrict__ w0, const float* __restrict__ b0,
    const float* __restrict__ w1, const float* __restrict__ b1,
    const float* __restrict__ w2, const float* __restrict__ b2,
    const float* __restrict__ w3, const float* __restrict__ b3,
    const float* __restrict__ w4, const float* __restrict__ b4,
    const float* __restrict__ w5, const float* __restrict__ b5,
    bf16* __restrict__ pc, int cb)
{
  __shared__ __align__(16) bf16 Xs[128][128];
  __shared__ __align__(16) bf16 Ws[128][64];
  const int pt = blockIdx.x, b = blockIdx.y;
  const int tid = threadIdx.x;
  const int c0 = (tid >> 4) * 4;
  const int p0 = (tid & 15) * 8;

  #pragma unroll
  for (int mat = 0; mat < 6; ++mat) {
    const float* Wm; const float* Bm; const float* X;
    switch (mat) {
      case 0: Wm = w0; Bm = b0; X = st;  break;
      case 1: Wm = w1; Bm = b1; X = st;  break;
      case 2: Wm = w2; Bm = b2; X = st;  break;
      case 3: Wm = w3; Bm = b3; X = phy; break;
      case 4: Wm = w4; Bm = b4; X = phy; break;
      default:Wm = w5; Bm = b5; X = phy; break;
    }
    __syncthreads();
    if (mat == 0 || mat == 3) {
      for (int e = tid; e < 128 * 128; e += 256) {
        int i = e >> 7, p = e & 127;
        Xs[i][p] = __float2bfloat16(X[((size_t)b * 128 + i) * 1024 + pt * 128 + p]);
      }
    }
    for (int e = tid; e < 64 * 128; e += 256) {
      int c = e >> 7, i = e & 127;
      Ws[i][c] = __float2bfloat16(Wm[(cb + c) * 128 + i]);
    }
    __syncthreads();

    float acc[4][8];
    #pragma unroll
    for (int a = 0; a < 4; ++a)
      #pragma unroll
      for (int d = 0; d < 8; ++d) acc[a][d] = 0.f;

    #pragma unroll 2
    for (int i = 0; i < 128; ++i) {
      BF4 wv; wv.u = *(const unsigned long long*)&Ws[i][c0];
      BF8 xv; xv.v = *(const int4*)&Xs[i][p0];
      float wf[4], xf[8];
      #pragma unroll
      for (int j = 0; j < 4; ++j) wf[j] = __bfloat162float(wv.h[j]);
      #pragma unroll
      for (int j = 0; j < 8; ++j) xf[j] = __bfloat162float(xv.h[j]);
      #pragma unroll
      for (int cc = 0; cc < 4; ++cc)
        #pragma unroll
        for (int pp = 0; pp < 8; ++pp)
          acc[cc][pp] = fmaf(wf[cc], xf[pp], acc[cc][pp]);
    }
    #pragma unroll
    for (int cc = 0; cc < 4; ++cc) {
      float bias = Bm[cb + c0 + cc];
      BF8 pk;
      #pragma unroll
      for (int pp = 0; pp < 8; ++pp) pk.h[pp] = __float2bfloat16(acc[cc][pp] + bias);
      *(int4*)&pc[(((size_t)mat * 128 + b) * 64 + c0 + cc) * 1024 + pt * 128 + p0] = pk.v;
    }
  }
}

// ---------------------------------------------------------------- attention helpers
DI void mm32(const float* A, int sa, const float* Bm, int sb,
             float acc[4][4], int r0, int c0)
{
  #pragma unroll 4
  for (int w = 0; w < 32; ++w) {
    float qv[4], kv[4];
    *(float4*)qv = *(const float4*)(A + w * sa + r0);
    *(float4*)kv = *(const float4*)(Bm + w * sb + c0);
    #pragma unroll
    for (int i = 0; i < 4; ++i)
      #pragma unroll
      for (int j = 0; j < 4; ++j)
        acc[i][j] = fmaf(qv[i], kv[j], acc[i][j]);
  }
}

DI void softmax4(float acc[4][4])
{
  #pragma unroll
  for (int i = 0; i < 4; ++i) {
    float m = fmaxf(fmaxf(acc[i][0], acc[i][1]), fmaxf(acc[i][2], acc[i][3]));
    m = fmaxf(m, __shfl_xor(m, 1));
    m = fmaxf(m, __shfl_xor(m, 2));
    m = fmaxf(m, __shfl_xor(m, 4));
    float s = 0.f;
    #pragma unroll
    for (int j = 0; j < 4; ++j) { acc[i][j] = __expf(acc[i][j] - m); s += acc[i][j]; }
    s += __shfl_xor(s, 1); s += __shfl_xor(s, 2); s += __shfl_xor(s, 4);
    float rs = 1.0f / s;
    #pragma unroll
    for (int j = 0; j < 4; ++j) acc[i][j] *= rs;
  }
}

template<bool U8OUT>
DI void attn_one(const float* Qt, const float* K, const float* V, float (*At)[36],
                 const float* resid, void* outp, int r0, int c0)
{
  float acc[4][4] = {};
  mm32(Qt, 36, K, 32, acc, r0, c0);
  softmax4(acc);
  __syncthreads();
  #pragma unroll
  for (int j = 0; j < 4; ++j)
    *(float4*)&At[c0 + j][r0] = make_float4(acc[0][j], acc[1][j], acc[2][j], acc[3][j]);
  __syncthreads();
  float o[4][4] = {};
  mm32(&At[0][0], 36, V, 32, o, r0, c0);
  softmax4(o);
  if constexpr (!U8OUT) {
    bf16* op = (bf16*)outp;
    if (resid) {
      #pragma unroll
      for (int i = 0; i < 4; ++i) {
        float4 rv = *(const float4*)&resid[(r0 + i) * 32 + c0];
        o[i][0] += rv.x; o[i][1] += rv.y; o[i][2] += rv.z; o[i][3] += rv.w;
      }
    }
    #pragma unroll
    for (int i = 0; i < 4; ++i) {
      BF4 pk;
      #pragma unroll
      for (int j = 0; j < 4; ++j) pk.h[j] = __float2bfloat16(o[i][j]);
      *(unsigned long long*)&op[(r0 + i) * 32 + c0] = pk.u;
    }
  } else {
    u8* op = (u8*)outp;
    #pragma unroll
    for (int i = 0; i < 4; ++i) {
      unsigned pk = 0;
      #pragma unroll
      for (int j = 0; j < 4; ++j) {
        unsigned bv = (unsigned)fminf(o[i][j] * 256.f + 0.5f, 255.f);
        pk |= bv << (8 * j);
      }
      *(unsigned*)&op[(r0 + i) * 32 + c0] = pk;
    }
  }
}

// ---------------------------------------------------------------- attention (64-ch chunk)
__global__ __launch_bounds__(64) void attn_chunk_kernel(
    const bf16* __restrict__ pc,
    const float* __restrict__ st, const float* __restrict__ phy,
    bf16* __restrict__ cA, u8* __restrict__ cB, int cb)
{
  __shared__ __align__(16) float Qst[32][36], Qphy[32][36];
  __shared__ __align__(16) float Kst[32][32], Kphy[32][32];
  __shared__ __align__(16) float Vst[32][32], Vphy[32][32];
  __shared__ __align__(16) float At[32][36];
  const int cl = blockIdx.x, b = blockIdx.y;
  const int c = cb + cl;
  const int lane = threadIdx.x;
  const size_t mstride = (size_t)128 * 64 * 1024;
  const bf16* p0 = pc + ((size_t)b * 64 + cl) * 1024;
  const size_t bc = ((size_t)b * 128 + c) * 1024;

  for (int e = lane; e < 1024; e += 64) {
    int h = e >> 5, w = e & 31;
    Qst[w][h]  = __bfloat162float(p0[e]);
    Kst[h][w]  = __bfloat162float(p0[mstride + e]);
    Vst[h][w]  = __bfloat162float(p0[2 * mstride + e]);
    Qphy[w][h] = __bfloat162float(p0[3 * mstride + e]);
    Kphy[h][w] = __bfloat162float(p0[4 * mstride + e]);
    Vphy[h][w] = __bfloat162float(p0[5 * mstride + e]);
  }
  __syncthreads();
  const int r0 = (lane >> 3) * 4, c0 = (lane & 7) * 4;
  bf16* aA = cA + (size_t)b * 256 * 1024 + (size_t)c * 1024;
  u8*   aB = cB + (size_t)b * 256 * 1024 + (size_t)c * 1024;

  attn_one<false>(&Qst[0][0],  &Kst[0][0],  &Vst[0][0],  At, st + bc,  aA,               r0, c0);
  attn_one<false>(&Qphy[0][0], &Kphy[0][0], &Vphy[0][0], At, phy + bc, aA + 128 * 1024,  r0, c0);
  attn_one<true >(&Qphy[0][0], &Kst[0][0],  &Vst[0][0],  At, nullptr,  aB,               r0, c0);
  attn_one<true >(&Qst[0][0],  &Kphy[0][0], &Vphy[0][0], At, nullptr,  aB + 128 * 1024,  r0, c0);
}

// ---------------------------------------------------------------- concat transpose -> [b][pos][ch]
__global__ __launch_bounds__(256) void transpose_kernel(
    const bf16* __restrict__ cA, const u8* __restrict__ cB,
    bf16* __restrict__ cAT, u8* __restrict__ cBT)
{
  __shared__ __align__(16) short Tb[64 * 72];
  __shared__ __align__(16) u8 T8[64 * 80];
  const int x = blockIdx.x, b = blockIdx.y;
  const int cht = x >> 4, post = x & 15;
  const int pos0 = post * 64;
  const int tid = threadIdx.x;
  const int rowi = tid >> 2, sub = tid & 3;

  if (cht < 4) {
    const int ch0 = cht * 64;
    const bf16* src = cA + ((size_t)b * 256 + ch0 + rowi) * 1024 + pos0 + sub * 16;
    *(int4*)&Tb[rowi * 72 + sub * 16]     = *(const int4*)src;
    *(int4*)&Tb[rowi * 72 + sub * 16 + 8] = *(const int4*)(src + 8);
    __syncthreads();
    short tmp[16];
    #pragma unroll
    for (int j = 0; j < 16; ++j) tmp[j] = Tb[(sub * 16 + j) * 72 + rowi];
    bf16* dst = cAT + ((size_t)b * 1024 + pos0 + rowi) * 256 + ch0 + sub * 16;
    *(int4*)dst       = ((int4*)tmp)[0];
    *(int4*)(dst + 8) = ((int4*)tmp)[1];
  } else {
    const int ch0 = (cht - 4) * 64;
    const u8* src = cB + ((size_t)b * 256 + ch0 + rowi) * 1024 + pos0 + sub * 16;
    *(int4*)&T8[rowi * 80 + sub * 16] = *(const int4*)src;
    __syncthreads();
    u8 tmp[16];
    #pragma unroll
    for (int j = 0; j < 16; ++j) tmp[j] = T8[(sub * 16 + j) * 80 + rowi];
    u8* dst = cBT + ((size_t)b * 1024 + pos0 + rowi) * 256 + ch0 + sub * 16;
    *(int4*)dst = *(int4*)tmp;
  }
}

// ---------------------------------------------------------------- MFMA conv k=3/5/7
// Block: 256 thr (4 waves) = 64 oc x 16 rows x 32 cols. Grid (4, 128): x = ot*2+rt.
// Wave: 2 oc-tiles x 4 rows -> acc 2x4 f32x16 = 128 VGPR.
// Input: ring-buffered LDS tile [16 row-slots][PCX cols][80 B entry = 32ic + pad].
//   Entry stride 80 B = 20 dwords: consecutive-lane b128 spans tile all 32 banks
//   every 8 lanes -> conflict-free reads AND writes (no swizzle).
// Weights: [tap][icg][128 oc][8 ic] -> coalesced dwordx4, 3.2 MB/block (L2-fits).
// Per (tap,kt): A-loads 2, B-reads 4, MFMA 8 -> L1 and LDS pipes both ~2x MFMA,
// running in parallel -> ~50% MfmaUtil design point.
template<int KS>
__global__ __launch_bounds__(256, 2) void conv_mfma(
    const bf16* __restrict__ cAT, const u8* __restrict__ cBT,
    const bf16* __restrict__ wt, bf16* __restrict__ xout,
    float* __restrict__ partials)
{
  constexpr int H0 = KS / 2;
  constexpr int PCX = 32 + 2 * H0;
  constexpr int NITEMS = 16 * PCX * 4;
  __shared__ __align__(16) short Xs[16 * PCX * 40];
  __shared__ float rs[256], rq[256];
  const int tix = blockIdx.x, b = blockIdx.y;
  const int ot = tix >> 1, rt = tix & 1;
  const int oc0 = ot * 64, r0 = rt * 16;
  const int tid = threadIdx.x;
  const int wv = tid >> 6, lane = tid & 63;
  const int col = lane & 31, kg = lane >> 5;

  f32x16 acc[2][4];
  #pragma unroll
  for (int i = 0; i < 2; ++i)
    #pragma unroll
    for (int j = 0; j < 4; ++j)
      #pragma unroll
      for (int e = 0; e < 16; ++e) acc[i][j][e] = 0.f;

  for (int cc = 0; cc < 16; ++cc) {
    const int ic0 = cc * 32;
    // ---- prologue stage: rows ir = r0-H0 .. r0-H0+15 into slot ir&15
    for (int e = tid; e < NITEMS; e += 256) {
      int i = e / (PCX * 4);
      int rem = e - i * (PCX * 4);
      int cx = rem >> 2, part = rem & 3;
      int ir = r0 - H0 + i, c = cx - H0;
      int4 val = make_int4(0, 0, 0, 0);
      if ((unsigned)ir < 32u && (unsigned)c < 32u) {
        size_t pbase = ((size_t)b * 1024 + ir * 32 + c) * 256;
        if (ic0 < 256) {
          val = *(const int4*)&cAT[pbase + ic0 + part * 8];
        } else {
          unsigned long long u = *(const unsigned long long*)&cBT[pbase + (ic0 - 256) + part * 8];
          BF8 t;
          #pragma unroll
          for (int j = 0; j < 8; ++j)
            t.h[j] = __float2bfloat16((float)((u >> (8 * j)) & 255u) * 0.00390625f);
          val = t.v;
        }
      }
      *(int4*)&Xs[((ir & 15) * PCX + cx) * 40 + part * 8] = val;
    }
    __syncthreads();

    for (int ky = 0; ky < KS; ++ky) {
      if (ky > 0) {
        // stage the one new row: ir = r0 - H0 + 15 + ky
        if (tid < PCX * 4) {
          int cx = tid >> 2, part = tid & 3;
          int ir = r0 - H0 + 15 + ky, c = cx - H0;
          int4 val = make_int4(0, 0, 0, 0);
          if ((unsigned)ir < 32u && (unsigned)c < 32u) {
            size_t pbase = ((size_t)b * 1024 + ir * 32 + c) * 256;
            if (ic0 < 256) {
              val = *(const int4*)&cAT[pbase + ic0 + part * 8];
            } else {
              unsigned long long u = *(const unsigned long long*)&cBT[pbase + (ic0 - 256) + part * 8];
              BF8 t;
              #pragma unroll
              for (int j = 0; j < 8; ++j)
                t.h[j] = __float2bfloat16((float)((u >> (8 * j)) & 255u) * 0.00390625f);
              val = t.v;
            }
          }
          *(int4*)&Xs[((ir & 15) * PCX + cx) * 40 + part * 8] = val;
        }
        __syncthreads();
      }

      #pragma unroll
      for (int kx = 0; kx < KS; ++kx) {
        const int tap = ky * KS + kx;
        BF8 a[2][2];
        #pragma unroll
        for (int ob = 0; ob < 2; ++ob)
          #pragma unroll
          for (int kt = 0; kt < 2; ++kt) {
            int icg = cc * 4 + kt * 2 + kg;
            a[ob][kt].v = *(const int4*)&wt[(((size_t)tap * 64 + icg) * 128 + oc0 + ob * 32 + col) * 8];
          }
        #pragma unroll
        for (int rr = 0; rr < 4; ++rr) {
          int ir = r0 + wv * 4 + rr + ky - H0;
          int entry = (ir & 15) * PCX + col + kx;
          #pragma unroll
          for (int kt = 0; kt < 2; ++kt) {
            short8 bf = *(const short8*)&Xs[entry * 40 + (kt * 2 + kg) * 8];
            acc[0][rr] = __builtin_amdgcn_mfma_f32_32x32x16_bf16(a[0][kt].s, bf, acc[0][rr], 0, 0, 0);
            acc[1][rr] = __builtin_amdgcn_mfma_f32_32x32x16_bf16(a[1][kt].s, bf, acc[1][rr], 0, 0, 0);
          }
        }
      }
      __syncthreads();   // protect ring slot reused by next stage / next cc
    }
  }

  float lsum = 0.f, lsq = 0.f;
  #pragma unroll
  for (int ob = 0; ob < 2; ++ob)
    #pragma unroll
    for (int rr = 0; rr < 4; ++rr) {
      const int row = r0 + wv * 4 + rr;
      #pragma unroll
      for (int r = 0; r < 16; ++r) {
        const int oc = oc0 + ob * 32 + (r & 3) + 8 * (r >> 2) + 4 * kg;
        float v = acc[ob][rr][r];
        xout[((size_t)b * 128 + oc) * 1024 + row * 32 + col] = __float2bfloat16(v);
        lsum += v; lsq += v * v;
      }
    }
  rs[tid] = lsum; rq[tid] = lsq;
  __syncthreads();
  for (int s = 128; s > 0; s >>= 1) {
    if (tid < s) { rs[tid] += rs[tid + s]; rq[tid] += rq[tid + s]; }
    __syncthreads();
  }
  if (tid == 0) {
    partials[((size_t)b * 4 + tix) * 2]     = rs[0];
    partials[((size_t)b * 4 + tix) * 2 + 1] = rq[0];
  }
}

// ---------------------------------------------------------------- MFMA conv k=1 + b1
__global__ __launch_bounds__(256) void conv1_mfma(
    const bf16* __restrict__ cAT, const u8* __restrict__ cBT,
    const bf16* __restrict__ w1T, const float* __restrict__ b1,
    bf16* __restrict__ xout, float* __restrict__ partials)
{
  __shared__ float rs[256], rq[256];
  const int pt = blockIdx.x, b = blockIdx.y;
  const int tid = threadIdx.x, wave = tid >> 6, lane = tid & 63;
  const int col = lane & 31, kg = lane >> 5;
  const int pos = pt * 128 + wave * 32 + col;

  f32x16 acc[4];
  #pragma unroll
  for (int i = 0; i < 4; ++i)
    #pragma unroll
    for (int e = 0; e < 16; ++e) acc[i][e] = 0.f;

  const bf16* wbase = w1T + (size_t)col * 512 + kg * 8;
  const size_t pbase = ((size_t)b * 1024 + pos) * 256;

  #pragma unroll 2
  for (int kst = 0; kst < 32; ++kst) {
    short8 bfr;
    if (kst < 16) {
      bfr = *(const short8*)&cAT[pbase + kst * 16 + kg * 8];
    } else {
      const u8* s = &cBT[pbase + (kst - 16) * 16 + kg * 8];
      unsigned lo = *(const unsigned*)s, hi = *(const unsigned*)(s + 4);
      BF8 t;
      #pragma unroll
      for (int j = 0; j < 4; ++j) t.h[j]     = __float2bfloat16((float)((lo >> (8 * j)) & 255u) * 0.00390625f);
      #pragma unroll
      for (int j = 0; j < 4; ++j) t.h[4 + j] = __float2bfloat16((float)((hi >> (8 * j)) & 255u) * 0.00390625f);
      bfr = t.s;
    }
    #pragma unroll
    for (int mf = 0; mf < 4; ++mf) {
      BF8 a; a.v = *(const int4*)&wbase[((size_t)mf * 32) * 512 + kst * 16];
      acc[mf] = __builtin_amdgcn_mfma_f32_32x32x16_bf16(a.s, bfr, acc[mf], 0, 0, 0);
    }
  }

  float lsum = 0.f, lsq = 0.f;
  #pragma unroll
  for (int mf = 0; mf < 4; ++mf) {
    #pragma unroll
    for (int r = 0; r < 16; ++r) {
      const int oc = mf * 32 + (r & 3) + 8 * (r >> 2) + 4 * kg;
      float v = acc[mf][r] + b1[oc];
      xout[((size_t)b * 128 + oc) * 1024 + pos] = __float2bfloat16(v);
      lsum += v; lsq += v * v;
    }
  }
  rs[tid] = lsum; rq[tid] = lsq;
  __syncthreads();
  for (int s = 128; s > 0; s >>= 1) {
    if (tid < s) { rs[tid] += rs[tid + s]; rq[tid] += rq[tid + s]; }
    __syncthreads();
  }
  if (tid == 0) {
    partials[((size_t)b * 8 + pt) * 2]     = rs[0];
    partials[((size_t)b * 8 + pt) * 2 + 1] = rq[0];
  }
}

// ---------------------------------------------------------------- LN + combine
__global__ __launch_bounds__(256) void final_kernel(
    const bf16* __restrict__ x3, const bf16* __restrict__ x5,
    const bf16* __restrict__ x7, const bf16* __restrict__ x1c,
    const float* __restrict__ p3, const float* __restrict__ p5,
    const float* __restrict__ p7, const float* __restrict__ p1,
    const float* __restrict__ g3, const float* __restrict__ be3,
    const float* __restrict__ g5, const float* __restrict__ be5,
    const float* __restrict__ g7, const float* __restrict__ be7,
    const float* __restrict__ g1, const float* __restrict__ be1,
    float* __restrict__ out)
{
  const int blk = blockIdx.x, b = blockIdx.y, tid = threadIdx.x;
  float s3 = 0, q3 = 0, s5 = 0, q5 = 0, s7 = 0, q7 = 0, s1 = 0, q1 = 0;
  #pragma unroll
  for (int i = 0; i < 4; ++i) {
    int o = (b * 4 + i) * 2;
    s3 += p3[o]; q3 += p3[o + 1];
    s5 += p5[o]; q5 += p5[o + 1];
    s7 += p7[o]; q7 += p7[o + 1];
  }
  #pragma unroll
  for (int i = 0; i < 8; ++i) {
    int o = (b * 8 + i) * 2;
    s1 += p1[o]; q1 += p1[o + 1];
  }
  const float inv = 1.0f / 131072.0f;
  float mu3 = s3 * inv, r3 = rsqrtf(fmaxf(q3 * inv - mu3 * mu3, 0.f) + 1e-5f);
  float mu5 = s5 * inv, r5 = rsqrtf(fmaxf(q5 * inv - mu5 * mu5, 0.f) + 1e-5f);
  float mu7 = s7 * inv, r7 = rsqrtf(fmaxf(q7 * inv - mu7 * mu7, 0.f) + 1e-5f);
  float mu1 = s1 * inv, r1 = rsqrtf(fmaxf(q1 * inv - mu1 * mu1, 0.f) + 1e-5f);
  const size_t bb = (size_t)b * 131072;
  for (int it = 0; it < 8; ++it) {
    int e0 = (it * 2048 + blk * 256 + tid) * 8;
    BF8 a3, a5, a7, a1;
    a3.v = *(const int4*)&x3[bb + e0];
    a5.v = *(const int4*)&x5[bb + e0];
    a7.v = *(const int4*)&x7[bb + e0];
    a1.v = *(const int4*)&x1c[bb + e0];
    float G3[8], B3[8], G5[8], B5[8], G7[8], B7[8], G1[8], B1[8];
    *(float4*)&G3[0] = *(const float4*)&g3[e0];  *(float4*)&G3[4] = *(const float4*)&g3[e0 + 4];
    *(float4*)&B3[0] = *(const float4*)&be3[e0]; *(float4*)&B3[4] = *(const float4*)&be3[e0 + 4];
    *(float4*)&G5[0] = *(const float4*)&g5[e0];  *(float4*)&G5[4] = *(const float4*)&g5[e0 + 4];
    *(float4*)&B5[0] = *(const float4*)&be5[e0]; *(float4*)&B5[4] = *(const float4*)&be5[e0 + 4];
    *(float4*)&G7[0] = *(const float4*)&g7[e0];  *(float4*)&G7[4] = *(const float4*)&g7[e0 + 4];
    *(float4*)&B7[0] = *(const float4*)&be7[e0]; *(float4*)&B7[4] = *(const float4*)&be7[e0 + 4];
    *(float4*)&G1[0] = *(const float4*)&g1[e0];  *(float4*)&G1[4] = *(const float4*)&g1[e0 + 4];
    *(float4*)&B1[0] = *(const float4*)&be1[e0]; *(float4*)&B1[4] = *(const float4*)&be1[e0 + 4];
    float res[8];
    #pragma unroll
    for (int j = 0; j < 8; ++j) {
      float v3 = (__bfloat162float(a3.h[j]) - mu3) * r3 * G3[j] + B3[j];
      float v5 = (__bfloat162float(a5.h[j]) - mu5) * r5 * G5[j] + B5[j];
      float v7 = (__bfloat162float(a7.h[j]) - mu7) * r7 * G7[j] + B7[j];
      float m = (v3 + v5 + v7) * (1.0f / 3.0f);
      float sg = 1.0f / (1.0f + __expf(-m));
      float v1 = (__bfloat162float(a1.h[j]) - mu1) * r1 * G1[j] + B1[j];
      res[j] = sg + v1;
    }
    *(float4*)&out[bb + e0]     = make_float4(res[0], res[1], res[2], res[3]);
    *(float4*)&out[bb + e0 + 4] = make_float4(res[4], res[5], res[6], res[7]);
  }
}

// ---------------------------------------------------------------- launch
extern "C" void kernel_launch(void* const* d_in, const int* in_sizes, int n_in,
                              void* d_out, int out_size, void* d_ws, size_t ws_size,
                              hipStream_t stream)
{
  (void)in_sizes; (void)n_in; (void)out_size; (void)ws_size;
  const float* st     = (const float*)d_in[0];
  const float* phy    = (const float*)d_in[1];
  const float* wq_st  = (const float*)d_in[2];
  const float* bq_st  = (const float*)d_in[3];
  const float* wk_st  = (const float*)d_in[4];
  const float* bk_st  = (const float*)d_in[5];
  const float* wv_st  = (const float*)d_in[6];
  const float* bv_st  = (const float*)d_in[7];
  const float* wq_phy = (const float*)d_in[8];
  const float* bq_phy = (const float*)d_in[9];
  const float* wk_phy = (const float*)d_in[10];
  const float* bk_phy = (const float*)d_in[11];
  const float* wv_phy = (const float*)d_in[12];
  const float* bv_phy = (const float*)d_in[13];
  const float* w3  = (const float*)d_in[14];
  const float* g3  = (const float*)d_in[15];
  const float* be3 = (const float*)d_in[16];
  const float* w5  = (const float*)d_in[17];
  const float* g5  = (const float*)d_in[18];
  const float* be5 = (const float*)d_in[19];
  const float* w7  = (const float*)d_in[20];
  const float* g7  = (const float*)d_in[21];
  const float* be7 = (const float*)d_in[22];
  const float* w1  = (const float*)d_in[23];
  const float* g1  = (const float*)d_in[24];
  const float* be1 = (const float*)d_in[25];
  const float* b1  = (const float*)d_in[26];

  char* ws = (char*)d_ws;
  bf16* cAT      = (bf16*)ws;
  u8*   cBT      = (u8*)(ws + 67108864ULL);
  bf16* projchunk = (bf16*)ws;                      // phase A only
  bf16* cA       = (bf16*)(ws + 100663296ULL);      // phase A only
  u8*   cB       = (u8*)(ws + 167772160ULL);        // phase A only
  bf16* x3b      = (bf16*)(ws + 100663296ULL);
  bf16* x5b      = (bf16*)(ws + 134217728ULL);
  bf16* x7b      = (bf16*)(ws + 167772160ULL);
  bf16* x1b      = (bf16*)(ws + 201326592ULL);
  float* parts   = (float*)(ws + 234881024ULL);
  bf16* wb3      = (bf16*)(ws + 234913792ULL);
  bf16* wb5      = (bf16*)(ws + 236093440ULL);
  bf16* wb7      = (bf16*)(ws + 239370240ULL);
  bf16* w1T      = (bf16*)(ws + 245792768ULL);

  prep_w_kernel<<<dim3(2048), 256, 0, stream>>>(w3, w5, w7, w1, wb3, wb5, wb7, w1T);

  for (int g = 0; g < 2; ++g) {
    proj_chunk_kernel<<<dim3(8, 128), 256, 0, stream>>>(st, phy,
        wq_st, bq_st, wk_st, bk_st, wv_st, bv_st,
        wq_phy, bq_phy, wk_phy, bk_phy, wv_phy, bv_phy, projchunk, g * 64);
    attn_chunk_kernel<<<dim3(64, 128), 64, 0, stream>>>(projchunk, st, phy,
        cA, cB, g * 64);
  }
  transpose_kernel<<<dim3(128, 128), 256, 0, stream>>>(cA, cB, cAT, cBT);

  conv_mfma<3><<<dim3(4, 128), 256, 0, stream>>>(cAT, cBT, wb3, x3b, parts);
  conv_mfma<5><<<dim3(4, 128), 256, 0, stream>>>(cAT, cBT, wb5, x5b, parts + 2048);
  conv_mfma<7><<<dim3(4, 128), 256, 0, stream>>>(cAT, cBT, wb7, x7b, parts + 4096);
  conv1_mfma<<<dim3(8, 128), 256, 0, stream>>>(cAT, cBT, w1T, b1, x1b, parts + 6144);

  final_kernel<<<dim3(8, 128), 256, 0, stream>>>(x3b, x5b, x7b, x1b,
      parts, parts + 2048, parts + 4096, parts + 6144,
      g3, be3, g5, be5, g7, be7, g1, be1, (float*)d_out);
}

// Round 6
// 2198.447 us; speedup vs baseline: 2.0862x; 1.1401x over previous
//
#include <hip/hip_runtime.h>
#include <hip/hip_bf16.h>

typedef __hip_bfloat16 bf16;
typedef unsigned char u8;
typedef __attribute__((ext_vector_type(8))) short short8;
typedef __attribute__((ext_vector_type(16))) float f32x16;
#define DI __device__ __forceinline__

union BF8 { int4 v; short8 s; bf16 h[8]; };
union BF4 { unsigned long long u; bf16 h[4]; };

// ws layout (bytes):
// phase A (xpose/proj/attn):
//   Xt bf16 [2][128 b][1024 pos][128 ic]   @ 0            (67,108,864)
//   projchunk bf16 [6][128][32][1024]      @ 67,108,864   (50,331,648)
//   cA bf16 [128][256][1024]               @ 117,440,512  (67,108,864)
//   cB u8   [128][256][1024]               @ 184,549,376  (33,554,432)  ends 218,103,808
//   wproj bf16 [6][128][128]               @ 218,103,808  (196,608)     (dead gap region)
// phase B (transpose): cAT bf16 @ 0 (67,108,864), cBT u8 @ 67,108,864 (33,554,432)
// phase C (convs): x3 @100,663,296  x5 @134,217,728  x7 @167,772,160  x1 @201,326,592
// parts f32 @ 234,881,024 (32 KB)
// wb3/wb5/wb7 bf16 [tap][64 icg][128 oc][8 ic] @ 234,913,792 / 236,093,440 / 239,370,240
// w1T bf16 [128][512] @ 245,792,768   (end 245,923,840)

// ---------------------------------------------------------------- weight prep
__global__ __launch_bounds__(256) void prep_w_kernel(
    const float* __restrict__ w3, const float* __restrict__ w5,
    const float* __restrict__ w7, const float* __restrict__ w1,
    const float* __restrict__ wq_st, const float* __restrict__ wk_st,
    const float* __restrict__ wv_st, const float* __restrict__ wq_phy,
    const float* __restrict__ wk_phy, const float* __restrict__ wv_phy,
    bf16* __restrict__ wb3, bf16* __restrict__ wb5,
    bf16* __restrict__ wb7, bf16* __restrict__ w1T, bf16* __restrict__ wp)
{
  const int N3 = 9 * 65536, N5 = 25 * 65536, N7 = 49 * 65536, N1 = 65536;
  const int NP = 6 * 16384;
  const int total = N3 + N5 + N7 + N1 + NP;
  for (int i = blockIdx.x * 256 + threadIdx.x; i < total; i += gridDim.x * 256) {
    if (i < N3) {
      int tap = i >> 16, rem = i & 65535;
      int icg = rem >> 10, oc = (rem >> 3) & 127, j = rem & 7;
      wb3[i] = __float2bfloat16(w3[(size_t)(oc * 512 + icg * 8 + j) * 9 + tap]);
    } else if (i < N3 + N5) {
      int k = i - N3; int tap = k >> 16, rem = k & 65535;
      int icg = rem >> 10, oc = (rem >> 3) & 127, j = rem & 7;
      wb5[k] = __float2bfloat16(w5[(size_t)(oc * 512 + icg * 8 + j) * 25 + tap]);
    } else if (i < N3 + N5 + N7) {
      int k = i - N3 - N5; int tap = k >> 16, rem = k & 65535;
      int icg = rem >> 10, oc = (rem >> 3) & 127, j = rem & 7;
      wb7[k] = __float2bfloat16(w7[(size_t)(oc * 512 + icg * 8 + j) * 49 + tap]);
    } else if (i < N3 + N5 + N7 + N1) {
      int k = i - N3 - N5 - N7;
      w1T[k] = __float2bfloat16(w1[k]);
    } else {
      int k = i - N3 - N5 - N7 - N1;
      int m = k >> 14, r = k & 16383;
      float v;
      switch (m) {
        case 0: v = wq_st[r]; break;
        case 1: v = wk_st[r]; break;
        case 2: v = wv_st[r]; break;
        case 3: v = wq_phy[r]; break;
        case 4: v = wk_phy[r]; break;
        default: v = wv_phy[r]; break;
      }
      wp[k] = __float2bfloat16(v);
    }
  }
}

// ---------------------------------------------------------------- input transpose
// st/phy fp32 [b][128 ic][1024 pos] -> Xt bf16 [t][b][1024 pos][128 ic]
__global__ __launch_bounds__(256) void xpose_in_kernel(
    const float* __restrict__ st, const float* __restrict__ phy,
    bf16* __restrict__ Xt)
{
  __shared__ __align__(16) short Tb[64 * 72];
  const int x = blockIdx.x, b = blockIdx.y;
  const int t = x >> 5, rem = x & 31;
  const int ict = rem >> 4, post = rem & 15;
  const int ic0 = ict * 64, pos0 = post * 64;
  const int tid = threadIdx.x;
  const int rowi = tid >> 2, sub = tid & 3;
  const float* X = t ? phy : st;

  const float* src = X + ((size_t)b * 128 + ic0 + rowi) * 1024 + pos0 + sub * 16;
  #pragma unroll
  for (int q = 0; q < 4; ++q) {
    float4 v = *(const float4*)(src + q * 4);
    BF4 pk;
    pk.h[0] = __float2bfloat16(v.x); pk.h[1] = __float2bfloat16(v.y);
    pk.h[2] = __float2bfloat16(v.z); pk.h[3] = __float2bfloat16(v.w);
    *(unsigned long long*)&Tb[rowi * 72 + sub * 16 + q * 4] = pk.u;
  }
  __syncthreads();
  short tmp[16];
  #pragma unroll
  for (int j = 0; j < 16; ++j) tmp[j] = Tb[(sub * 16 + j) * 72 + rowi];
  bf16* dst = Xt + (((size_t)t * 128 + b) * 1024 + pos0 + rowi) * 128 + ic0 + sub * 16;
  *(int4*)dst       = ((int4*)tmp)[0];
  *(int4*)(dst + 8) = ((int4*)tmp)[1];
}

// ---------------------------------------------------------------- MFMA projections (32-ch chunk)
// out[mat][b][c in chunk][pos] = sum_ic W[mat][cb+c][ic] * X[ic][pos] + bias
// Fragment pattern mirrors conv1_mfma (verified R3-R5).
__global__ __launch_bounds__(256) void proj_mfma(
    const bf16* __restrict__ Xt, const bf16* __restrict__ wproj,
    const float* __restrict__ b0, const float* __restrict__ b1,
    const float* __restrict__ b2, const float* __restrict__ b3,
    const float* __restrict__ b4, const float* __restrict__ b5,
    bf16* __restrict__ pc, int cb)
{
  const int pt = blockIdx.x, b = blockIdx.y;
  const int tid = threadIdx.x, wave = tid >> 6, lane = tid & 63;
  const int col = lane & 31, kg = lane >> 5;
  const int pos = pt * 128 + wave * 32 + col;

  f32x16 acc[6];
  #pragma unroll
  for (int m = 0; m < 6; ++m)
    #pragma unroll
    for (int e = 0; e < 16; ++e) acc[m][e] = 0.f;

  const bf16* xst = Xt + ((size_t)b * 1024 + pos) * 128 + kg * 8;
  const bf16* xph = xst + (size_t)128 * 1024 * 128;
  const bf16* wl = wproj + (size_t)(cb + col) * 128 + kg * 8;

  #pragma unroll
  for (int kst = 0; kst < 8; ++kst) {
    short8 bst = *(const short8*)&xst[kst * 16];
    short8 bph = *(const short8*)&xph[kst * 16];
    #pragma unroll
    for (int m = 0; m < 6; ++m) {
      BF8 a; a.v = *(const int4*)&wl[(size_t)m * 16384 + kst * 16];
      acc[m] = __builtin_amdgcn_mfma_f32_32x32x16_bf16(a.s, m < 3 ? bst : bph, acc[m], 0, 0, 0);
    }
  }
  const float* biases[6] = { b0, b1, b2, b3, b4, b5 };
  #pragma unroll
  for (int m = 0; m < 6; ++m) {
    #pragma unroll
    for (int r = 0; r < 16; ++r) {
      const int ocl = (r & 3) + 8 * (r >> 2) + 4 * kg;
      float v = acc[m][r] + biases[m][cb + ocl];
      pc[(((size_t)m * 128 + b) * 32 + ocl) * 1024 + pos] = __float2bfloat16(v);
    }
  }
}

// ---------------------------------------------------------------- attention helpers
DI void mm32(const float* A, int sa, const float* Bm, int sb,
             float acc[4][4], int r0, int c0)
{
  #pragma unroll 4
  for (int w = 0; w < 32; ++w) {
    float qv[4], kv[4];
    *(float4*)qv = *(const float4*)(A + w * sa + r0);
    *(float4*)kv = *(const float4*)(Bm + w * sb + c0);
    #pragma unroll
    for (int i = 0; i < 4; ++i)
      #pragma unroll
      for (int j = 0; j < 4; ++j)
        acc[i][j] = fmaf(qv[i], kv[j], acc[i][j]);
  }
}

DI void softmax4(float acc[4][4])
{
  #pragma unroll
  for (int i = 0; i < 4; ++i) {
    float m = fmaxf(fmaxf(acc[i][0], acc[i][1]), fmaxf(acc[i][2], acc[i][3]));
    m = fmaxf(m, __shfl_xor(m, 1));
    m = fmaxf(m, __shfl_xor(m, 2));
    m = fmaxf(m, __shfl_xor(m, 4));
    float s = 0.f;
    #pragma unroll
    for (int j = 0; j < 4; ++j) { acc[i][j] = __expf(acc[i][j] - m); s += acc[i][j]; }
    s += __shfl_xor(s, 1); s += __shfl_xor(s, 2); s += __shfl_xor(s, 4);
    float rs = 1.0f / s;
    #pragma unroll
    for (int j = 0; j < 4; ++j) acc[i][j] *= rs;
  }
}

template<bool U8OUT>
DI void attn_one(const float* Qt, const float* K, const float* V, float (*At)[36],
                 const float* resid, void* outp, int r0, int c0)
{
  float acc[4][4] = {};
  mm32(Qt, 36, K, 32, acc, r0, c0);
  softmax4(acc);
  __syncthreads();
  #pragma unroll
  for (int j = 0; j < 4; ++j)
    *(float4*)&At[c0 + j][r0] = make_float4(acc[0][j], acc[1][j], acc[2][j], acc[3][j]);
  __syncthreads();
  float o[4][4] = {};
  mm32(&At[0][0], 36, V, 32, o, r0, c0);
  softmax4(o);
  if constexpr (!U8OUT) {
    bf16* op = (bf16*)outp;
    if (resid) {
      #pragma unroll
      for (int i = 0; i < 4; ++i) {
        float4 rv = *(const float4*)&resid[(r0 + i) * 32 + c0];
        o[i][0] += rv.x; o[i][1] += rv.y; o[i][2] += rv.z; o[i][3] += rv.w;
      }
    }
    #pragma unroll
    for (int i = 0; i < 4; ++i) {
      BF4 pk;
      #pragma unroll
      for (int j = 0; j < 4; ++j) pk.h[j] = __float2bfloat16(o[i][j]);
      *(unsigned long long*)&op[(r0 + i) * 32 + c0] = pk.u;
    }
  } else {
    u8* op = (u8*)outp;
    #pragma unroll
    for (int i = 0; i < 4; ++i) {
      unsigned pk = 0;
      #pragma unroll
      for (int j = 0; j < 4; ++j) {
        unsigned bv = (unsigned)fminf(o[i][j] * 256.f + 0.5f, 255.f);
        pk |= bv << (8 * j);
      }
      *(unsigned*)&op[(r0 + i) * 32 + c0] = pk;
    }
  }
}

// ---------------------------------------------------------------- attention (32-ch chunk)
__global__ __launch_bounds__(64) void attn_chunk_kernel(
    const bf16* __restrict__ pc,
    const float* __restrict__ st, const float* __restrict__ phy,
    bf16* __restrict__ cA, u8* __restrict__ cB, int cb)
{
  __shared__ __align__(16) float Qst[32][36], Qphy[32][36];
  __shared__ __align__(16) float Kst[32][32], Kphy[32][32];
  __shared__ __align__(16) float Vst[32][32], Vphy[32][32];
  __shared__ __align__(16) float At[32][36];
  const int cl = blockIdx.x, b = blockIdx.y;
  const int c = cb + cl;
  const int lane = threadIdx.x;
  const size_t mstride = (size_t)128 * 32 * 1024;
  const bf16* p0 = pc + ((size_t)b * 32 + cl) * 1024;
  const size_t bc = ((size_t)b * 128 + c) * 1024;

  for (int e = lane; e < 1024; e += 64) {
    int h = e >> 5, w = e & 31;
    Qst[w][h]  = __bfloat162float(p0[e]);
    Kst[h][w]  = __bfloat162float(p0[mstride + e]);
    Vst[h][w]  = __bfloat162float(p0[2 * mstride + e]);
    Qphy[w][h] = __bfloat162float(p0[3 * mstride + e]);
    Kphy[h][w] = __bfloat162float(p0[4 * mstride + e]);
    Vphy[h][w] = __bfloat162float(p0[5 * mstride + e]);
  }
  __syncthreads();
  const int r0 = (lane >> 3) * 4, c0 = (lane & 7) * 4;
  bf16* aA = cA + (size_t)b * 256 * 1024 + (size_t)c * 1024;
  u8*   aB = cB + (size_t)b * 256 * 1024 + (size_t)c * 1024;

  attn_one<false>(&Qst[0][0],  &Kst[0][0],  &Vst[0][0],  At, st + bc,  aA,               r0, c0);
  attn_one<false>(&Qphy[0][0], &Kphy[0][0], &Vphy[0][0], At, phy + bc, aA + 128 * 1024,  r0, c0);
  attn_one<true >(&Qphy[0][0], &Kst[0][0],  &Vst[0][0],  At, nullptr,  aB,               r0, c0);
  attn_one<true >(&Qst[0][0],  &Kphy[0][0], &Vphy[0][0], At, nullptr,  aB + 128 * 1024,  r0, c0);
}

// ---------------------------------------------------------------- concat transpose -> [b][pos][ch]
__global__ __launch_bounds__(256) void transpose_kernel(
    const bf16* __restrict__ cA, const u8* __restrict__ cB,
    bf16* __restrict__ cAT, u8* __restrict__ cBT)
{
  __shared__ __align__(16) short Tb[64 * 72];
  __shared__ __align__(16) u8 T8[64 * 80];
  const int x = blockIdx.x, b = blockIdx.y;
  const int cht = x >> 4, post = x & 15;
  const int pos0 = post * 64;
  const int tid = threadIdx.x;
  const int rowi = tid >> 2, sub = tid & 3;

  if (cht < 4) {
    const int ch0 = cht * 64;
    const bf16* src = cA + ((size_t)b * 256 + ch0 + rowi) * 1024 + pos0 + sub * 16;
    *(int4*)&Tb[rowi * 72 + sub * 16]     = *(const int4*)src;
    *(int4*)&Tb[rowi * 72 + sub * 16 + 8] = *(const int4*)(src + 8);
    __syncthreads();
    short tmp[16];
    #pragma unroll
    for (int j = 0; j < 16; ++j) tmp[j] = Tb[(sub * 16 + j) * 72 + rowi];
    bf16* dst = cAT + ((size_t)b * 1024 + pos0 + rowi) * 256 + ch0 + sub * 16;
    *(int4*)dst       = ((int4*)tmp)[0];
    *(int4*)(dst + 8) = ((int4*)tmp)[1];
  } else {
    const int ch0 = (cht - 4) * 64;
    const u8* src = cB + ((size_t)b * 256 + ch0 + rowi) * 1024 + pos0 + sub * 16;
    *(int4*)&T8[rowi * 80 + sub * 16] = *(const int4*)src;
    __syncthreads();
    u8 tmp[16];
    #pragma unroll
    for (int j = 0; j < 16; ++j) tmp[j] = T8[(sub * 16 + j) * 80 + rowi];
    u8* dst = cBT + ((size_t)b * 1024 + pos0 + rowi) * 256 + ch0 + sub * 16;
    *(int4*)dst = *(int4*)tmp;
  }
}

// ---------------------------------------------------------------- MFMA conv k=3/5/7
// Block: 256 thr (4 waves) = 64 oc x 16 rows x 32 cols. Grid (4, 128): x = ot*2+rt.
// Full halo tile [16+2H0 rows][PCX][80 B] staged per cc -> 2 barriers per cc
// (was 2*KS). 80 B entry stride => conflict-free-ish b128 access (R5-proven).
template<int KS>
__global__ __launch_bounds__(256, 2) void conv_mfma(
    const bf16* __restrict__ cAT, const u8* __restrict__ cBT,
    const bf16* __restrict__ wt, bf16* __restrict__ xout,
    float* __restrict__ partials)
{
  constexpr int H0 = KS / 2;
  constexpr int PCX = 32 + 2 * H0;
  constexpr int ROWS = 16 + 2 * H0;
  constexpr int NIT = ROWS * PCX * 4;
  __shared__ __align__(16) short Xs[ROWS * PCX * 40];
  __shared__ float rs[256], rq[256];
  const int tix = blockIdx.x, b = blockIdx.y;
  const int ot = tix >> 1, rt = tix & 1;
  const int oc0 = ot * 64, r0 = rt * 16;
  const int tid = threadIdx.x;
  const int wv = tid >> 6, lane = tid & 63;
  const int col = lane & 31, kg = lane >> 5;

  f32x16 acc[2][4];
  #pragma unroll
  for (int i = 0; i < 2; ++i)
    #pragma unroll
    for (int j = 0; j < 4; ++j)
      #pragma unroll
      for (int e = 0; e < 16; ++e) acc[i][j][e] = 0.f;

  for (int cc = 0; cc < 16; ++cc) {
    const int ic0 = cc * 32;
    for (int e = tid; e < NIT; e += 256) {
      int i = e / (PCX * 4);
      int rem = e - i * (PCX * 4);
      int cx = rem >> 2, part = rem & 3;
      int ir = r0 - H0 + i, c = cx - H0;
      int4 val = make_int4(0, 0, 0, 0);
      if ((unsigned)ir < 32u && (unsigned)c < 32u) {
        size_t pbase = ((size_t)b * 1024 + ir * 32 + c) * 256;
        if (ic0 < 256) {
          val = *(const int4*)&cAT[pbase + ic0 + part * 8];
        } else {
          unsigned long long u = *(const unsigned long long*)&cBT[pbase + (ic0 - 256) + part * 8];
          BF8 t;
          #pragma unroll
          for (int j = 0; j < 8; ++j)
            t.h[j] = __float2bfloat16((float)((u >> (8 * j)) & 255u) * 0.00390625f);
          val = t.v;
        }
      }
      *(int4*)&Xs[(i * PCX + cx) * 40 + part * 8] = val;
    }
    __syncthreads();

    #pragma unroll 1
    for (int ky = 0; ky < KS; ++ky) {
      #pragma unroll
      for (int kx = 0; kx < KS; ++kx) {
        const int tap = ky * KS + kx;
        BF8 a[2][2];
        #pragma unroll
        for (int ob = 0; ob < 2; ++ob)
          #pragma unroll
          for (int kt = 0; kt < 2; ++kt) {
            int icg = cc * 4 + kt * 2 + kg;
            a[ob][kt].v = *(const int4*)&wt[(((size_t)tap * 64 + icg) * 128 + oc0 + ob * 32 + col) * 8];
          }
        #pragma unroll
        for (int rr = 0; rr < 4; ++rr) {
          int entry = ((wv * 4 + rr + ky) * PCX + col + kx) * 40;
          #pragma unroll
          for (int kt = 0; kt < 2; ++kt) {
            short8 bf = *(const short8*)&Xs[entry + (kt * 2 + kg) * 8];
            acc[0][rr] = __builtin_amdgcn_mfma_f32_32x32x16_bf16(a[0][kt].s, bf, acc[0][rr], 0, 0, 0);
            acc[1][rr] = __builtin_amdgcn_mfma_f32_32x32x16_bf16(a[1][kt].s, bf, acc[1][rr], 0, 0, 0);
          }
        }
      }
    }
    __syncthreads();   // Xs reused by next cc's staging
  }

  float lsum = 0.f, lsq = 0.f;
  #pragma unroll
  for (int ob = 0; ob < 2; ++ob)
    #pragma unroll
    for (int rr = 0; rr < 4; ++rr) {
      const int row = r0 + wv * 4 + rr;
      #pragma unroll
      for (int r = 0; r < 16; ++r) {
        const int oc = oc0 + ob * 32 + (r & 3) + 8 * (r >> 2) + 4 * kg;
        float v = acc[ob][rr][r];
        xout[((size_t)b * 128 + oc) * 1024 + row * 32 + col] = __float2bfloat16(v);
        lsum += v; lsq += v * v;
      }
    }
  rs[tid] = lsum; rq[tid] = lsq;
  __syncthreads();
  for (int s = 128; s > 0; s >>= 1) {
    if (tid < s) { rs[tid] += rs[tid + s]; rq[tid] += rq[tid + s]; }
    __syncthreads();
  }
  if (tid == 0) {
    partials[((size_t)b * 4 + tix) * 2]     = rs[0];
    partials[((size_t)b * 4 + tix) * 2 + 1] = rq[0];
  }
}

// ---------------------------------------------------------------- MFMA conv k=1 + b1
__global__ __launch_bounds__(256) void conv1_mfma(
    const bf16* __restrict__ cAT, const u8* __restrict__ cBT,
    const bf16* __restrict__ w1T, const float* __restrict__ b1,
    bf16* __restrict__ xout, float* __restrict__ partials)
{
  __shared__ float rs[256], rq[256];
  const int pt = blockIdx.x, b = blockIdx.y;
  const int tid = threadIdx.x, wave = tid >> 6, lane = tid & 63;
  const int col = lane & 31, kg = lane >> 5;
  const int pos = pt * 128 + wave * 32 + col;

  f32x16 acc[4];
  #pragma unroll
  for (int i = 0; i < 4; ++i)
    #pragma unroll
    for (int e = 0; e < 16; ++e) acc[i][e] = 0.f;

  const bf16* wbase = w1T + (size_t)col * 512 + kg * 8;
  const size_t pbase = ((size_t)b * 1024 + pos) * 256;

  #pragma unroll 2
  for (int kst = 0; kst < 32; ++kst) {
    short8 bfr;
    if (kst < 16) {
      bfr = *(const short8*)&cAT[pbase + kst * 16 + kg * 8];
    } else {
      const u8* s = &cBT[pbase + (kst - 16) * 16 + kg * 8];
      unsigned lo = *(const unsigned*)s, hi = *(const unsigned*)(s + 4);
      BF8 t;
      #pragma unroll
      for (int j = 0; j < 4; ++j) t.h[j]     = __float2bfloat16((float)((lo >> (8 * j)) & 255u) * 0.00390625f);
      #pragma unroll
      for (int j = 0; j < 4; ++j) t.h[4 + j] = __float2bfloat16((float)((hi >> (8 * j)) & 255u) * 0.00390625f);
      bfr = t.s;
    }
    #pragma unroll
    for (int mf = 0; mf < 4; ++mf) {
      BF8 a; a.v = *(const int4*)&wbase[((size_t)mf * 32) * 512 + kst * 16];
      acc[mf] = __builtin_amdgcn_mfma_f32_32x32x16_bf16(a.s, bfr, acc[mf], 0, 0, 0);
    }
  }

  float lsum = 0.f, lsq = 0.f;
  #pragma unroll
  for (int mf = 0; mf < 4; ++mf) {
    #pragma unroll
    for (int r = 0; r < 16; ++r) {
      const int oc = mf * 32 + (r & 3) + 8 * (r >> 2) + 4 * kg;
      float v = acc[mf][r] + b1[oc];
      xout[((size_t)b * 128 + oc) * 1024 + pos] = __float2bfloat16(v);
      lsum += v; lsq += v * v;
    }
  }
  rs[tid] = lsum; rq[tid] = lsq;
  __syncthreads();
  for (int s = 128; s > 0; s >>= 1) {
    if (tid < s) { rs[tid] += rs[tid + s]; rq[tid] += rq[tid + s]; }
    __syncthreads();
  }
  if (tid == 0) {
    partials[((size_t)b * 8 + pt) * 2]     = rs[0];
    partials[((size_t)b * 8 + pt) * 2 + 1] = rq[0];
  }
}

// ---------------------------------------------------------------- LN + combine
__global__ __launch_bounds__(256) void final_kernel(
    const bf16* __restrict__ x3, const bf16* __restrict__ x5,
    const bf16* __restrict__ x7, const bf16* __restrict__ x1c,
    const float* __restrict__ p3, const float* __restrict__ p5,
    const float* __restrict__ p7, const float* __restrict__ p1,
    const float* __restrict__ g3, const float* __restrict__ be3,
    const float* __restrict__ g5, const float* __restrict__ be5,
    const float* __restrict__ g7, const float* __restrict__ be7,
    const float* __restrict__ g1, const float* __restrict__ be1,
    float* __restrict__ out)
{
  const int blk = blockIdx.x, b = blockIdx.y, tid = threadIdx.x;
  float s3 = 0, q3 = 0, s5 = 0, q5 = 0, s7 = 0, q7 = 0, s1 = 0, q1 = 0;
  #pragma unroll
  for (int i = 0; i < 4; ++i) {
    int o = (b * 4 + i) * 2;
    s3 += p3[o]; q3 += p3[o + 1];
    s5 += p5[o]; q5 += p5[o + 1];
    s7 += p7[o]; q7 += p7[o + 1];
  }
  #pragma unroll
  for (int i = 0; i < 8; ++i) {
    int o = (b * 8 + i) * 2;
    s1 += p1[o]; q1 += p1[o + 1];
  }
  const float inv = 1.0f / 131072.0f;
  float mu3 = s3 * inv, r3 = rsqrtf(fmaxf(q3 * inv - mu3 * mu3, 0.f) + 1e-5f);
  float mu5 = s5 * inv, r5 = rsqrtf(fmaxf(q5 * inv - mu5 * mu5, 0.f) + 1e-5f);
  float mu7 = s7 * inv, r7 = rsqrtf(fmaxf(q7 * inv - mu7 * mu7, 0.f) + 1e-5f);
  float mu1 = s1 * inv, r1 = rsqrtf(fmaxf(q1 * inv - mu1 * mu1, 0.f) + 1e-5f);
  const size_t bb = (size_t)b * 131072;
  for (int it = 0; it < 8; ++it) {
    int e0 = (it * 2048 + blk * 256 + tid) * 8;
    BF8 a3, a5, a7, a1;
    a3.v = *(const int4*)&x3[bb + e0];
    a5.v = *(const int4*)&x5[bb + e0];
    a7.v = *(const int4*)&x7[bb + e0];
    a1.v = *(const int4*)&x1c[bb + e0];
    float G3[8], B3[8], G5[8], B5[8], G7[8], B7[8], G1[8], B1[8];
    *(float4*)&G3[0] = *(const float4*)&g3[e0];  *(float4*)&G3[4] = *(const float4*)&g3[e0 + 4];
    *(float4*)&B3[0] = *(const float4*)&be3[e0]; *(float4*)&B3[4] = *(const float4*)&be3[e0 + 4];
    *(float4*)&G5[0] = *(const float4*)&g5[e0];  *(float4*)&G5[4] = *(const float4*)&g5[e0 + 4];
    *(float4*)&B5[0] = *(const float4*)&be5[e0]; *(float4*)&B5[4] = *(const float4*)&be5[e0 + 4];
    *(float4*)&G7[0] = *(const float4*)&g7[e0];  *(float4*)&G7[4] = *(const float4*)&g7[e0 + 4];
    *(float4*)&B7[0] = *(const float4*)&be7[e0]; *(float4*)&B7[4] = *(const float4*)&be7[e0 + 4];
    *(float4*)&G1[0] = *(const float4*)&g1[e0];  *(float4*)&G1[4] = *(const float4*)&g1[e0 + 4];
    *(float4*)&B1[0] = *(const float4*)&be1[e0]; *(float4*)&B1[4] = *(const float4*)&be1[e0 + 4];
    float res[8];
    #pragma unroll
    for (int j = 0; j < 8; ++j) {
      float v3 = (__bfloat162float(a3.h[j]) - mu3) * r3 * G3[j] + B3[j];
      float v5 = (__bfloat162float(a5.h[j]) - mu5) * r5 * G5[j] + B5[j];
      float v7 = (__bfloat162float(a7.h[j]) - mu7) * r7 * G7[j] + B7[j];
      float m = (v3 + v5 + v7) * (1.0f / 3.0f);
      float sg = 1.0f / (1.0f + __expf(-m));
      float v1 = (__bfloat162float(a1.h[j]) - mu1) * r1 * G1[j] + B1[j];
      res[j] = sg + v1;
    }
    *(float4*)&out[bb + e0]     = make_float4(res[0], res[1], res[2], res[3]);
    *(float4*)&out[bb + e0 + 4] = make_float4(res[4], res[5], res[6], res[7]);
  }
}

// ---------------------------------------------------------------- launch
extern "C" void kernel_launch(void* const* d_in, const int* in_sizes, int n_in,
                              void* d_out, int out_size, void* d_ws, size_t ws_size,
                              hipStream_t stream)
{
  (void)in_sizes; (void)n_in; (void)out_size; (void)ws_size;
  const float* st     = (const float*)d_in[0];
  const float* phy    = (const float*)d_in[1];
  const float* wq_st  = (const float*)d_in[2];
  const float* bq_st  = (const float*)d_in[3];
  const float* wk_st  = (const float*)d_in[4];
  const float* bk_st  = (const float*)d_in[5];
  const float* wv_st  = (const float*)d_in[6];
  const float* bv_st  = (const float*)d_in[7];
  const float* wq_phy = (const float*)d_in[8];
  const float* bq_phy = (const float*)d_in[9];
  const float* wk_phy = (const float*)d_in[10];
  const float* bk_phy = (const float*)d_in[11];
  const float* wv_phy = (const float*)d_in[12];
  const float* bv_phy = (const float*)d_in[13];
  const float* w3  = (const float*)d_in[14];
  const float* g3  = (const float*)d_in[15];
  const float* be3 = (const float*)d_in[16];
  const float* w5  = (const float*)d_in[17];
  const float* g5  = (const float*)d_in[18];
  const float* be5 = (const float*)d_in[19];
  const float* w7  = (const float*)d_in[20];
  const float* g7  = (const float*)d_in[21];
  const float* be7 = (const float*)d_in[22];
  const float* w1  = (const float*)d_in[23];
  const float* g1  = (const float*)d_in[24];
  const float* be1 = (const float*)d_in[25];
  const float* b1  = (const float*)d_in[26];

  char* ws = (char*)d_ws;
  bf16* Xt        = (bf16*)ws;                       // phase A
  bf16* projchunk = (bf16*)(ws + 67108864ULL);       // phase A
  bf16* cA        = (bf16*)(ws + 117440512ULL);      // phase A
  u8*   cB        = (u8*)(ws + 184549376ULL);        // phase A
  bf16* wproj     = (bf16*)(ws + 218103808ULL);      // phase A (dead gap)
  bf16* cAT       = (bf16*)ws;                       // phase B/C
  u8*   cBT       = (u8*)(ws + 67108864ULL);         // phase B/C
  bf16* x3b       = (bf16*)(ws + 100663296ULL);
  bf16* x5b       = (bf16*)(ws + 134217728ULL);
  bf16* x7b       = (bf16*)(ws + 167772160ULL);
  bf16* x1b       = (bf16*)(ws + 201326592ULL);
  float* parts    = (float*)(ws + 234881024ULL);
  bf16* wb3       = (bf16*)(ws + 234913792ULL);
  bf16* wb5       = (bf16*)(ws + 236093440ULL);
  bf16* wb7       = (bf16*)(ws + 239370240ULL);
  bf16* w1T       = (bf16*)(ws + 245792768ULL);

  prep_w_kernel<<<dim3(2048), 256, 0, stream>>>(w3, w5, w7, w1,
      wq_st, wk_st, wv_st, wq_phy, wk_phy, wv_phy,
      wb3, wb5, wb7, w1T, wproj);
  xpose_in_kernel<<<dim3(64, 128), 256, 0, stream>>>(st, phy, Xt);

  for (int g = 0; g < 4; ++g) {
    proj_mfma<<<dim3(8, 128), 256, 0, stream>>>(Xt, wproj,
        bq_st, bk_st, bv_st, bq_phy, bk_phy, bv_phy, projchunk, g * 32);
    attn_chunk_kernel<<<dim3(32, 128), 64, 0, stream>>>(projchunk, st, phy,
        cA, cB, g * 32);
  }
  transpose_kernel<<<dim3(128, 128), 256, 0, stream>>>(cA, cB, cAT, cBT);

  conv_mfma<3><<<dim3(4, 128), 256, 0, stream>>>(cAT, cBT, wb3, x3b, parts);
  conv_mfma<5><<<dim3(4, 128), 256, 0, stream>>>(cAT, cBT, wb5, x5b, parts + 2048);
  conv_mfma<7><<<dim3(4, 128), 256, 0, stream>>>(cAT, cBT, wb7, x7b, parts + 4096);
  conv1_mfma<<<dim3(8, 128), 256, 0, stream>>>(cAT, cBT, w1T, b1, x1b, parts + 6144);

  final_kernel<<<dim3(8, 128), 256, 0, stream>>>(x3b, x5b, x7b, x1b,
      parts, parts + 2048, parts + 4096, parts + 6144,
      g3, be3, g5, be5, g7, be7, g1, be1, (float*)d_out);
}

// Round 7
// 2166.522 us; speedup vs baseline: 2.1170x; 1.0147x over previous
//
#include <hip/hip_runtime.h>
#include <hip/hip_bf16.h>

typedef __hip_bfloat16 bf16;
typedef unsigned char u8;
typedef __attribute__((ext_vector_type(8))) short short8;
typedef __attribute__((ext_vector_type(16))) float f32x16;
#define DI __device__ __forceinline__

union BF8 { int4 v; short8 s; bf16 h[8]; };
union BF4 { unsigned long long u; bf16 h[4]; };

// ws layout (bytes):
// phase A (xpose/proj/attn):
//   Xt bf16 [2][128 b][1024 pos][128 ic]   @ 0            (67,108,864)
//   projchunk bf16 [6][128][32][1024]      @ 67,108,864   (50,331,648)
//   cA bf16 [128][256][1024]               @ 117,440,512  (67,108,864)
//   cB u8   [128][256][1024]               @ 184,549,376  (33,554,432)  ends 218,103,808
//   wproj bf16 [6][128][128]               @ 218,103,808  (196,608)
// phase B (transpose): cAT bf16 @ 0 (67,108,864), cBT u8 @ 67,108,864 (33,554,432)
// phase C (convs): x3 @100,663,296  x5 @134,217,728  x7 @167,772,160  x1 @201,326,592
// parts f32 @ 234,881,024 (32 KB)
// wb3/wb5/wb7 bf16 [tap][64 icg][128 oc][8 ic] @ 234,913,792 / 236,093,440 / 239,370,240
// wb1 bf16 [64 icg][128 oc][8 ic] @ 245,792,768  (end 245,923,840)

// ---------------------------------------------------------------- weight prep
__global__ __launch_bounds__(256) void prep_w_kernel(
    const float* __restrict__ w3, const float* __restrict__ w5,
    const float* __restrict__ w7, const float* __restrict__ w1,
    const float* __restrict__ wq_st, const float* __restrict__ wk_st,
    const float* __restrict__ wv_st, const float* __restrict__ wq_phy,
    const float* __restrict__ wk_phy, const float* __restrict__ wv_phy,
    bf16* __restrict__ wb3, bf16* __restrict__ wb5,
    bf16* __restrict__ wb7, bf16* __restrict__ wb1, bf16* __restrict__ wp)
{
  const int N3 = 9 * 65536, N5 = 25 * 65536, N7 = 49 * 65536, N1 = 65536;
  const int NP = 6 * 16384;
  const int total = N3 + N5 + N7 + N1 + NP;
  for (int i = blockIdx.x * 256 + threadIdx.x; i < total; i += gridDim.x * 256) {
    if (i < N3) {
      int tap = i >> 16, rem = i & 65535;
      int icg = rem >> 10, oc = (rem >> 3) & 127, j = rem & 7;
      wb3[i] = __float2bfloat16(w3[(size_t)(oc * 512 + icg * 8 + j) * 9 + tap]);
    } else if (i < N3 + N5) {
      int k = i - N3; int tap = k >> 16, rem = k & 65535;
      int icg = rem >> 10, oc = (rem >> 3) & 127, j = rem & 7;
      wb5[k] = __float2bfloat16(w5[(size_t)(oc * 512 + icg * 8 + j) * 25 + tap]);
    } else if (i < N3 + N5 + N7) {
      int k = i - N3 - N5; int tap = k >> 16, rem = k & 65535;
      int icg = rem >> 10, oc = (rem >> 3) & 127, j = rem & 7;
      wb7[k] = __float2bfloat16(w7[(size_t)(oc * 512 + icg * 8 + j) * 49 + tap]);
    } else if (i < N3 + N5 + N7 + N1) {
      int k = i - N3 - N5 - N7;
      int icg = k >> 10, oc = (k >> 3) & 127, j = k & 7;
      wb1[k] = __float2bfloat16(w1[(size_t)oc * 512 + icg * 8 + j]);
    } else {
      int k = i - N3 - N5 - N7 - N1;
      int m = k >> 14, r = k & 16383;
      float v;
      switch (m) {
        case 0: v = wq_st[r]; break;
        case 1: v = wk_st[r]; break;
        case 2: v = wv_st[r]; break;
        case 3: v = wq_phy[r]; break;
        case 4: v = wk_phy[r]; break;
        default: v = wv_phy[r]; break;
      }
      wp[k] = __float2bfloat16(v);
    }
  }
}

// ---------------------------------------------------------------- input transpose
__global__ __launch_bounds__(256) void xpose_in_kernel(
    const float* __restrict__ st, const float* __restrict__ phy,
    bf16* __restrict__ Xt)
{
  __shared__ __align__(16) short Tb[64 * 72];
  const int x = blockIdx.x, b = blockIdx.y;
  const int t = x >> 5, rem = x & 31;
  const int ict = rem >> 4, post = rem & 15;
  const int ic0 = ict * 64, pos0 = post * 64;
  const int tid = threadIdx.x;
  const int rowi = tid >> 2, sub = tid & 3;
  const float* X = t ? phy : st;

  const float* src = X + ((size_t)b * 128 + ic0 + rowi) * 1024 + pos0 + sub * 16;
  #pragma unroll
  for (int q = 0; q < 4; ++q) {
    float4 v = *(const float4*)(src + q * 4);
    BF4 pk;
    pk.h[0] = __float2bfloat16(v.x); pk.h[1] = __float2bfloat16(v.y);
    pk.h[2] = __float2bfloat16(v.z); pk.h[3] = __float2bfloat16(v.w);
    *(unsigned long long*)&Tb[rowi * 72 + sub * 16 + q * 4] = pk.u;
  }
  __syncthreads();
  short tmp[16];
  #pragma unroll
  for (int j = 0; j < 16; ++j) tmp[j] = Tb[(sub * 16 + j) * 72 + rowi];
  bf16* dst = Xt + (((size_t)t * 128 + b) * 1024 + pos0 + rowi) * 128 + ic0 + sub * 16;
  *(int4*)dst       = ((int4*)tmp)[0];
  *(int4*)(dst + 8) = ((int4*)tmp)[1];
}

// ---------------------------------------------------------------- MFMA projections (32-ch chunk)
__global__ __launch_bounds__(256) void proj_mfma(
    const bf16* __restrict__ Xt, const bf16* __restrict__ wproj,
    const float* __restrict__ b0, const float* __restrict__ b1,
    const float* __restrict__ b2, const float* __restrict__ b3,
    const float* __restrict__ b4, const float* __restrict__ b5,
    bf16* __restrict__ pc, int cb)
{
  const int pt = blockIdx.x, b = blockIdx.y;
  const int tid = threadIdx.x, wave = tid >> 6, lane = tid & 63;
  const int col = lane & 31, kg = lane >> 5;
  const int pos = pt * 128 + wave * 32 + col;

  f32x16 acc[6];
  #pragma unroll
  for (int m = 0; m < 6; ++m)
    #pragma unroll
    for (int e = 0; e < 16; ++e) acc[m][e] = 0.f;

  const bf16* xst = Xt + ((size_t)b * 1024 + pos) * 128 + kg * 8;
  const bf16* xph = xst + (size_t)128 * 1024 * 128;
  const bf16* wl = wproj + (size_t)(cb + col) * 128 + kg * 8;

  #pragma unroll
  for (int kst = 0; kst < 8; ++kst) {
    short8 bst = *(const short8*)&xst[kst * 16];
    short8 bph = *(const short8*)&xph[kst * 16];
    #pragma unroll
    for (int m = 0; m < 6; ++m) {
      BF8 a; a.v = *(const int4*)&wl[(size_t)m * 16384 + kst * 16];
      acc[m] = __builtin_amdgcn_mfma_f32_32x32x16_bf16(a.s, m < 3 ? bst : bph, acc[m], 0, 0, 0);
    }
  }
  const float* biases[6] = { b0, b1, b2, b3, b4, b5 };
  #pragma unroll
  for (int m = 0; m < 6; ++m) {
    #pragma unroll
    for (int r = 0; r < 16; ++r) {
      const int ocl = (r & 3) + 8 * (r >> 2) + 4 * kg;
      float v = acc[m][r] + biases[m][cb + ocl];
      pc[(((size_t)m * 128 + b) * 32 + ocl) * 1024 + pos] = __float2bfloat16(v);
    }
  }
}

// ---------------------------------------------------------------- attention helpers (bf16 LDS)
DI void mm32b(const bf16* A, const bf16* Bm, float acc[4][4], int r0, int c0)
{
  #pragma unroll 4
  for (int w = 0; w < 32; ++w) {
    BF4 qa, kb;
    qa.u = *(const unsigned long long*)(A + w * 40 + r0);
    kb.u = *(const unsigned long long*)(Bm + w * 40 + c0);
    float qv[4], kv[4];
    #pragma unroll
    for (int j = 0; j < 4; ++j) {
      qv[j] = __bfloat162float(qa.h[j]);
      kv[j] = __bfloat162float(kb.h[j]);
    }
    #pragma unroll
    for (int i = 0; i < 4; ++i)
      #pragma unroll
      for (int j = 0; j < 4; ++j)
        acc[i][j] = fmaf(qv[i], kv[j], acc[i][j]);
  }
}

DI void softmax4(float acc[4][4])
{
  #pragma unroll
  for (int i = 0; i < 4; ++i) {
    float m = fmaxf(fmaxf(acc[i][0], acc[i][1]), fmaxf(acc[i][2], acc[i][3]));
    m = fmaxf(m, __shfl_xor(m, 1));
    m = fmaxf(m, __shfl_xor(m, 2));
    m = fmaxf(m, __shfl_xor(m, 4));
    float s = 0.f;
    #pragma unroll
    for (int j = 0; j < 4; ++j) { acc[i][j] = __expf(acc[i][j] - m); s += acc[i][j]; }
    s += __shfl_xor(s, 1); s += __shfl_xor(s, 2); s += __shfl_xor(s, 4);
    float rs = 1.0f / s;
    #pragma unroll
    for (int j = 0; j < 4; ++j) acc[i][j] *= rs;
  }
}

template<bool U8OUT>
DI void attn_one(const bf16* Qt, const bf16* K, const bf16* V, bf16 (*At)[40],
                 const float* resid, void* outp, int r0, int c0)
{
  float acc[4][4] = {};
  mm32b(Qt, K, acc, r0, c0);
  softmax4(acc);
  __syncthreads();
  #pragma unroll
  for (int j = 0; j < 4; ++j) {
    BF4 pk;
    #pragma unroll
    for (int i = 0; i < 4; ++i) pk.h[i] = __float2bfloat16(acc[i][j]);
    *(unsigned long long*)&At[c0 + j][r0] = pk.u;
  }
  __syncthreads();
  float o[4][4] = {};
  mm32b(&At[0][0], V, o, r0, c0);
  softmax4(o);
  if constexpr (!U8OUT) {
    bf16* op = (bf16*)outp;
    if (resid) {
      #pragma unroll
      for (int i = 0; i < 4; ++i) {
        float4 rv = *(const float4*)&resid[(r0 + i) * 32 + c0];
        o[i][0] += rv.x; o[i][1] += rv.y; o[i][2] += rv.z; o[i][3] += rv.w;
      }
    }
    #pragma unroll
    for (int i = 0; i < 4; ++i) {
      BF4 pk;
      #pragma unroll
      for (int j = 0; j < 4; ++j) pk.h[j] = __float2bfloat16(o[i][j]);
      *(unsigned long long*)&op[(r0 + i) * 32 + c0] = pk.u;
    }
  } else {
    u8* op = (u8*)outp;
    #pragma unroll
    for (int i = 0; i < 4; ++i) {
      unsigned pk = 0;
      #pragma unroll
      for (int j = 0; j < 4; ++j) {
        unsigned bv = (unsigned)fminf(o[i][j] * 256.f + 0.5f, 255.f);
        pk |= bv << (8 * j);
      }
      *(unsigned*)&op[(r0 + i) * 32 + c0] = pk;
    }
  }
}

// ---------------------------------------------------------------- attention (32-ch chunk)
// bf16 LDS (17.9 KB/block -> ~8 blocks/CU) + vectorized int4 staging.
__global__ __launch_bounds__(64) void attn_chunk_kernel(
    const bf16* __restrict__ pc,
    const float* __restrict__ st, const float* __restrict__ phy,
    bf16* __restrict__ cA, u8* __restrict__ cB, int cb)
{
  __shared__ __align__(16) bf16 Qst[32][40], Qph[32][40];
  __shared__ __align__(16) bf16 Kst[32][40], Kph[32][40];
  __shared__ __align__(16) bf16 Vst[32][40], Vph[32][40];
  __shared__ __align__(16) bf16 At[32][40];
  const int cl = blockIdx.x, b = blockIdx.y;
  const int c = cb + cl;
  const int lane = threadIdx.x;
  const size_t mstride = (size_t)128 * 32 * 1024;
  const bf16* p0 = pc + ((size_t)b * 32 + cl) * 1024;
  const size_t bc = ((size_t)b * 128 + c) * 1024;

  // vectorized staging: 2 int4 per lane per stream
  #pragma unroll
  for (int it = 0; it < 2; ++it) {
    int e8 = (it * 64 + lane) * 8;        // 8-elem group start
    int h = e8 >> 5, w0 = e8 & 31;
    BF8 q1, k1, v1, q2, k2, v2;
    q1.v = *(const int4*)&p0[e8];
    k1.v = *(const int4*)&p0[mstride + e8];
    v1.v = *(const int4*)&p0[2 * mstride + e8];
    q2.v = *(const int4*)&p0[3 * mstride + e8];
    k2.v = *(const int4*)&p0[4 * mstride + e8];
    v2.v = *(const int4*)&p0[5 * mstride + e8];
    *(int4*)&Kst[h][w0] = k1.v;
    *(int4*)&Vst[h][w0] = v1.v;
    *(int4*)&Kph[h][w0] = k2.v;
    *(int4*)&Vph[h][w0] = v2.v;
    #pragma unroll
    for (int j = 0; j < 8; ++j) {         // Q transposed scatter
      Qst[w0 + j][h] = q1.h[j];
      Qph[w0 + j][h] = q2.h[j];
    }
  }
  __syncthreads();
  const int r0 = (lane >> 3) * 4, c0 = (lane & 7) * 4;
  bf16* aA = cA + (size_t)b * 256 * 1024 + (size_t)c * 1024;
  u8*   aB = cB + (size_t)b * 256 * 1024 + (size_t)c * 1024;

  attn_one<false>(&Qst[0][0], &Kst[0][0], &Vst[0][0], At, st + bc,  aA,              r0, c0);
  attn_one<false>(&Qph[0][0], &Kph[0][0], &Vph[0][0], At, phy + bc, aA + 128 * 1024, r0, c0);
  attn_one<true >(&Qph[0][0], &Kst[0][0], &Vst[0][0], At, nullptr,  aB,              r0, c0);
  attn_one<true >(&Qst[0][0], &Kph[0][0], &Vph[0][0], At, nullptr,  aB + 128 * 1024, r0, c0);
}

// ---------------------------------------------------------------- concat transpose -> [b][pos][ch]
__global__ __launch_bounds__(256) void transpose_kernel(
    const bf16* __restrict__ cA, const u8* __restrict__ cB,
    bf16* __restrict__ cAT, u8* __restrict__ cBT)
{
  __shared__ __align__(16) short Tb[64 * 72];
  __shared__ __align__(16) u8 T8[64 * 80];
  const int x = blockIdx.x, b = blockIdx.y;
  const int cht = x >> 4, post = x & 15;
  const int pos0 = post * 64;
  const int tid = threadIdx.x;
  const int rowi = tid >> 2, sub = tid & 3;

  if (cht < 4) {
    const int ch0 = cht * 64;
    const bf16* src = cA + ((size_t)b * 256 + ch0 + rowi) * 1024 + pos0 + sub * 16;
    *(int4*)&Tb[rowi * 72 + sub * 16]     = *(const int4*)src;
    *(int4*)&Tb[rowi * 72 + sub * 16 + 8] = *(const int4*)(src + 8);
    __syncthreads();
    short tmp[16];
    #pragma unroll
    for (int j = 0; j < 16; ++j) tmp[j] = Tb[(sub * 16 + j) * 72 + rowi];
    bf16* dst = cAT + ((size_t)b * 1024 + pos0 + rowi) * 256 + ch0 + sub * 16;
    *(int4*)dst       = ((int4*)tmp)[0];
    *(int4*)(dst + 8) = ((int4*)tmp)[1];
  } else {
    const int ch0 = (cht - 4) * 64;
    const u8* src = cB + ((size_t)b * 256 + ch0 + rowi) * 1024 + pos0 + sub * 16;
    *(int4*)&T8[rowi * 80 + sub * 16] = *(const int4*)src;
    __syncthreads();
    u8 tmp[16];
    #pragma unroll
    for (int j = 0; j < 16; ++j) tmp[j] = T8[(sub * 16 + j) * 80 + rowi];
    u8* dst = cBT + ((size_t)b * 1024 + pos0 + rowi) * 256 + ch0 + sub * 16;
    *(int4*)dst = *(int4*)tmp;
  }
}

// ---------------------------------------------------------------- MFMA conv (KS = 1/3/5/7)
template<int KS>
__global__ __launch_bounds__(256, 2) void conv_mfma(
    const bf16* __restrict__ cAT, const u8* __restrict__ cBT,
    const bf16* __restrict__ wt, const float* __restrict__ bias,
    bf16* __restrict__ xout, float* __restrict__ partials)
{
  constexpr int H0 = KS / 2;
  constexpr int PCX = 32 + 2 * H0;
  constexpr int ROWS = 16 + 2 * H0;
  constexpr int NIT = ROWS * PCX * 4;
  __shared__ __align__(16) short Xs[ROWS * PCX * 40];
  __shared__ float rs[256], rq[256];
  const int tix = blockIdx.x, b = blockIdx.y;
  const int ot = tix >> 1, rt = tix & 1;
  const int oc0 = ot * 64, r0 = rt * 16;
  const int tid = threadIdx.x;
  const int wv = tid >> 6, lane = tid & 63;
  const int col = lane & 31, kg = lane >> 5;

  f32x16 acc[2][4];
  #pragma unroll
  for (int i = 0; i < 2; ++i)
    #pragma unroll
    for (int j = 0; j < 4; ++j)
      #pragma unroll
      for (int e = 0; e < 16; ++e) acc[i][j][e] = 0.f;

  for (int cc = 0; cc < 16; ++cc) {
    const int ic0 = cc * 32;
    for (int e = tid; e < NIT; e += 256) {
      int i = e / (PCX * 4);
      int rem = e - i * (PCX * 4);
      int cx = rem >> 2, part = rem & 3;
      int ir = r0 - H0 + i, c = cx - H0;
      int4 val = make_int4(0, 0, 0, 0);
      if ((unsigned)ir < 32u && (unsigned)c < 32u) {
        size_t pbase = ((size_t)b * 1024 + ir * 32 + c) * 256;
        if (ic0 < 256) {
          val = *(const int4*)&cAT[pbase + ic0 + part * 8];
        } else {
          unsigned long long u = *(const unsigned long long*)&cBT[pbase + (ic0 - 256) + part * 8];
          BF8 t;
          #pragma unroll
          for (int j = 0; j < 8; ++j)
            t.h[j] = __float2bfloat16((float)((u >> (8 * j)) & 255u) * 0.00390625f);
          val = t.v;
        }
      }
      *(int4*)&Xs[(i * PCX + cx) * 40 + part * 8] = val;
    }
    __syncthreads();

    #pragma unroll 1
    for (int ky = 0; ky < KS; ++ky) {
      #pragma unroll
      for (int kx = 0; kx < KS; ++kx) {
        const int tap = ky * KS + kx;
        BF8 a[2][2];
        #pragma unroll
        for (int ob = 0; ob < 2; ++ob)
          #pragma unroll
          for (int kt = 0; kt < 2; ++kt) {
            int icg = cc * 4 + kt * 2 + kg;
            a[ob][kt].v = *(const int4*)&wt[(((size_t)tap * 64 + icg) * 128 + oc0 + ob * 32 + col) * 8];
          }
        #pragma unroll
        for (int rr = 0; rr < 4; ++rr) {
          int entry = ((wv * 4 + rr + ky) * PCX + col + kx) * 40;
          #pragma unroll
          for (int kt = 0; kt < 2; ++kt) {
            short8 bf = *(const short8*)&Xs[entry + (kt * 2 + kg) * 8];
            acc[0][rr] = __builtin_amdgcn_mfma_f32_32x32x16_bf16(a[0][kt].s, bf, acc[0][rr], 0, 0, 0);
            acc[1][rr] = __builtin_amdgcn_mfma_f32_32x32x16_bf16(a[1][kt].s, bf, acc[1][rr], 0, 0, 0);
          }
        }
      }
    }
    __syncthreads();
  }

  float lsum = 0.f, lsq = 0.f;
  #pragma unroll
  for (int ob = 0; ob < 2; ++ob)
    #pragma unroll
    for (int rr = 0; rr < 4; ++rr) {
      const int row = r0 + wv * 4 + rr;
      #pragma unroll
      for (int r = 0; r < 16; ++r) {
        const int oc = oc0 + ob * 32 + (r & 3) + 8 * (r >> 2) + 4 * kg;
        float v = acc[ob][rr][r];
        if (bias) v += bias[oc];
        xout[((size_t)b * 128 + oc) * 1024 + row * 32 + col] = __float2bfloat16(v);
        lsum += v; lsq += v * v;
      }
    }
  rs[tid] = lsum; rq[tid] = lsq;
  __syncthreads();
  for (int s = 128; s > 0; s >>= 1) {
    if (tid < s) { rs[tid] += rs[tid + s]; rq[tid] += rq[tid + s]; }
    __syncthreads();
  }
  if (tid == 0) {
    partials[((size_t)b * 4 + tix) * 2]     = rs[0];
    partials[((size_t)b * 4 + tix) * 2 + 1] = rq[0];
  }
}

// ---------------------------------------------------------------- LN + combine
__global__ __launch_bounds__(256) void final_kernel(
    const bf16* __restrict__ x3, const bf16* __restrict__ x5,
    const bf16* __restrict__ x7, const bf16* __restrict__ x1c,
    const float* __restrict__ p3, const float* __restrict__ p5,
    const float* __restrict__ p7, const float* __restrict__ p1,
    const float* __restrict__ g3, const float* __restrict__ be3,
    const float* __restrict__ g5, const float* __restrict__ be5,
    const float* __restrict__ g7, const float* __restrict__ be7,
    const float* __restrict__ g1, const float* __restrict__ be1,
    float* __restrict__ out)
{
  const int blk = blockIdx.x, b = blockIdx.y, tid = threadIdx.x;
  float s3 = 0, q3 = 0, s5 = 0, q5 = 0, s7 = 0, q7 = 0, s1 = 0, q1 = 0;
  #pragma unroll
  for (int i = 0; i < 4; ++i) {
    int o = (b * 4 + i) * 2;
    s3 += p3[o]; q3 += p3[o + 1];
    s5 += p5[o]; q5 += p5[o + 1];
    s7 += p7[o]; q7 += p7[o + 1];
    s1 += p1[o]; q1 += p1[o + 1];
  }
  const float inv = 1.0f / 131072.0f;
  float mu3 = s3 * inv, r3 = rsqrtf(fmaxf(q3 * inv - mu3 * mu3, 0.f) + 1e-5f);
  float mu5 = s5 * inv, r5 = rsqrtf(fmaxf(q5 * inv - mu5 * mu5, 0.f) + 1e-5f);
  float mu7 = s7 * inv, r7 = rsqrtf(fmaxf(q7 * inv - mu7 * mu7, 0.f) + 1e-5f);
  float mu1 = s1 * inv, r1 = rsqrtf(fmaxf(q1 * inv - mu1 * mu1, 0.f) + 1e-5f);
  const size_t bb = (size_t)b * 131072;
  for (int it = 0; it < 8; ++it) {
    int e0 = (it * 2048 + blk * 256 + tid) * 8;
    BF8 a3, a5, a7, a1;
    a3.v = *(const int4*)&x3[bb + e0];
    a5.v = *(const int4*)&x5[bb + e0];
    a7.v = *(const int4*)&x7[bb + e0];
    a1.v = *(const int4*)&x1c[bb + e0];
    float G3[8], B3[8], G5[8], B5[8], G7[8], B7[8], G1[8], B1[8];
    *(float4*)&G3[0] = *(const float4*)&g3[e0];  *(float4*)&G3[4] = *(const float4*)&g3[e0 + 4];
    *(float4*)&B3[0] = *(const float4*)&be3[e0]; *(float4*)&B3[4] = *(const float4*)&be3[e0 + 4];
    *(float4*)&G5[0] = *(const float4*)&g5[e0];  *(float4*)&G5[4] = *(const float4*)&g5[e0 + 4];
    *(float4*)&B5[0] = *(const float4*)&be5[e0]; *(float4*)&B5[4] = *(const float4*)&be5[e0 + 4];
    *(float4*)&G7[0] = *(const float4*)&g7[e0];  *(float4*)&G7[4] = *(const float4*)&g7[e0 + 4];
    *(float4*)&B7[0] = *(const float4*)&be7[e0]; *(float4*)&B7[4] = *(const float4*)&be7[e0 + 4];
    *(float4*)&G1[0] = *(const float4*)&g1[e0];  *(float4*)&G1[4] = *(const float4*)&g1[e0 + 4];
    *(float4*)&B1[0] = *(const float4*)&be1[e0]; *(float4*)&B1[4] = *(const float4*)&be1[e0 + 4];
    float res[8];
    #pragma unroll
    for (int j = 0; j < 8; ++j) {
      float v3 = (__bfloat162float(a3.h[j]) - mu3) * r3 * G3[j] + B3[j];
      float v5 = (__bfloat162float(a5.h[j]) - mu5) * r5 * G5[j] + B5[j];
      float v7 = (__bfloat162float(a7.h[j]) - mu7) * r7 * G7[j] + B7[j];
      float m = (v3 + v5 + v7) * (1.0f / 3.0f);
      float sg = 1.0f / (1.0f + __expf(-m));
      float v1 = (__bfloat162float(a1.h[j]) - mu1) * r1 * G1[j] + B1[j];
      res[j] = sg + v1;
    }
    *(float4*)&out[bb + e0]     = make_float4(res[0], res[1], res[2], res[3]);
    *(float4*)&out[bb + e0 + 4] = make_float4(res[4], res[5], res[6], res[7]);
  }
}

// ---------------------------------------------------------------- launch
extern "C" void kernel_launch(void* const* d_in, const int* in_sizes, int n_in,
                              void* d_out, int out_size, void* d_ws, size_t ws_size,
                              hipStream_t stream)
{
  (void)in_sizes; (void)n_in; (void)out_size; (void)ws_size;
  const float* st     = (const float*)d_in[0];
  const float* phy    = (const float*)d_in[1];
  const float* wq_st  = (const float*)d_in[2];
  const float* bq_st  = (const float*)d_in[3];
  const float* wk_st  = (const float*)d_in[4];
  const float* bk_st  = (const float*)d_in[5];
  const float* wv_st  = (const float*)d_in[6];
  const float* bv_st  = (const float*)d_in[7];
  const float* wq_phy = (const float*)d_in[8];
  const float* bq_phy = (const float*)d_in[9];
  const float* wk_phy = (const float*)d_in[10];
  const float* bk_phy = (const float*)d_in[11];
  const float* wv_phy = (const float*)d_in[12];
  const float* bv_phy = (const float*)d_in[13];
  const float* w3  = (const float*)d_in[14];
  const float* g3  = (const float*)d_in[15];
  const float* be3 = (const float*)d_in[16];
  const float* w5  = (const float*)d_in[17];
  const float* g5  = (const float*)d_in[18];
  const float* be5 = (const float*)d_in[19];
  const float* w7  = (const float*)d_in[20];
  const float* g7  = (const float*)d_in[21];
  const float* be7 = (const float*)d_in[22];
  const float* w1  = (const float*)d_in[23];
  const float* g1  = (const float*)d_in[24];
  const float* be1 = (const float*)d_in[25];
  const float* b1  = (const float*)d_in[26];

  char* ws = (char*)d_ws;
  bf16* Xt        = (bf16*)ws;                       // phase A
  bf16* projchunk = (bf16*)(ws + 67108864ULL);       // phase A
  bf16* cA        = (bf16*)(ws + 117440512ULL);      // phase A
  u8*   cB        = (u8*)(ws + 184549376ULL);        // phase A
  bf16* wproj     = (bf16*)(ws + 218103808ULL);      // phase A (dead gap)
  bf16* cAT       = (bf16*)ws;                       // phase B/C
  u8*   cBT       = (u8*)(ws + 67108864ULL);         // phase B/C
  bf16* x3b       = (bf16*)(ws + 100663296ULL);
  bf16* x5b       = (bf16*)(ws + 134217728ULL);
  bf16* x7b       = (bf16*)(ws + 167772160ULL);
  bf16* x1b       = (bf16*)(ws + 201326592ULL);
  float* parts    = (float*)(ws + 234881024ULL);
  bf16* wb3       = (bf16*)(ws + 234913792ULL);
  bf16* wb5       = (bf16*)(ws + 236093440ULL);
  bf16* wb7       = (bf16*)(ws + 239370240ULL);
  bf16* wb1       = (bf16*)(ws + 245792768ULL);

  prep_w_kernel<<<dim3(2048), 256, 0, stream>>>(w3, w5, w7, w1,
      wq_st, wk_st, wv_st, wq_phy, wk_phy, wv_phy,
      wb3, wb5, wb7, wb1, wproj);
  xpose_in_kernel<<<dim3(64, 128), 256, 0, stream>>>(st, phy, Xt);

  for (int g = 0; g < 4; ++g) {
    proj_mfma<<<dim3(8, 128), 256, 0, stream>>>(Xt, wproj,
        bq_st, bk_st, bv_st, bq_phy, bk_phy, bv_phy, projchunk, g * 32);
    attn_chunk_kernel<<<dim3(32, 128), 64, 0, stream>>>(projchunk, st, phy,
        cA, cB, g * 32);
  }
  transpose_kernel<<<dim3(128, 128), 256, 0, stream>>>(cA, cB, cAT, cBT);

  conv_mfma<3><<<dim3(4, 128), 256, 0, stream>>>(cAT, cBT, wb3, nullptr, x3b, parts);
  conv_mfma<5><<<dim3(4, 128), 256, 0, stream>>>(cAT, cBT, wb5, nullptr, x5b, parts + 2048);
  conv_mfma<7><<<dim3(4, 128), 256, 0, stream>>>(cAT, cBT, wb7, nullptr, x7b, parts + 4096);
  conv_mfma<1><<<dim3(4, 128), 256, 0, stream>>>(cAT, cBT, wb1, b1, x1b, parts + 6144);

  final_kernel<<<dim3(8, 128), 256, 0, stream>>>(x3b, x5b, x7b, x1b,
      parts, parts + 2048, parts + 4096, parts + 6144,
      g3, be3, g5, be5, g7, be7, g1, be1, (float*)d_out);
}